// Round 1
// baseline (2464.884 us; speedup 1.0000x reference)
//
#include <hip/hip_runtime.h>
#include <hip/hip_bf16.h>
#include <math.h>

// ---------------- problem constants ----------------
#define NCN   5000      // customer nodes
#define NTN   10000     // target nodes
#define NEDGE 50000     // edges per direction
#define NLBL  20000     // label edges
// EMB = OUT = 64, EF = 16, L = 2

// float atomic max via int/uint monotonic reinterpretation
__device__ __forceinline__ void atomicMaxF(float* addr, float v) {
  if (v >= 0.0f) atomicMax((int*)addr, __float_as_int(v));
  else           atomicMin((unsigned int*)addr, __float_as_uint(v));
}

__global__ __launch_bounds__(256) void fill_neginf(float* __restrict__ p, int n) {
  int i = blockIdx.x * 256 + threadIdx.x;
  if (i < n) p[i] = -INFINITY;
}

// h[node] = emb[idx[node]] @ w(64x64) + b   (one wave per node)
__global__ __launch_bounds__(256) void node_transform(
    const float* __restrict__ emb, const int* __restrict__ idx,
    const float* __restrict__ w, const float* __restrict__ b,
    float* __restrict__ hout, int n)
{
  __shared__ float s_w[64 * 64];
  __shared__ float s_b[64];
  int tid = threadIdx.x;
  for (int i = tid; i < 4096; i += 256) s_w[i] = w[i];
  if (tid < 64) s_b[tid] = b[tid];
  __syncthreads();
  int wave = tid >> 6, lane = tid & 63;
  int node = blockIdx.x * 4 + wave;
  if (node >= n) return;
  float v = emb[idx[node] * 64 + lane];
  float acc = s_b[lane];
  #pragma unroll 8
  for (int i = 0; i < 64; ++i)
    acc = fmaf(__shfl(v, i, 64), s_w[i * 64 + lane], acc);
  hout[node * 64 + lane] = acc;
}

// NNConv message pass for a tile of 64 edges:
//   hidden = relu(eattr @ m1w + m1b)                       (in LDS)
//   msg[e,o] = sum_h hidden[e,h] * (sum_i hv[e,i]*m2w[h,i*64+o])
//            + sum_i hv[e,i]*m2b[i*64+o]
//   atomicMax into agg[dst[e]]
// Structured as GEMM [64 x 4096] @ [4096 x 64] with A generated on the fly:
// K-slice h: A[e][i] = hidden[e,h]*hv[e,i], B = m2w row h as [i][o].
__global__ __launch_bounds__(256) void conv_msg(
    const float* __restrict__ h_src,
    const int* __restrict__ esrc, const int* __restrict__ edst,
    const float* __restrict__ eattr,
    const float* __restrict__ m1w, const float* __restrict__ m1b,   // 16x64, 64
    const float* __restrict__ m2w, const float* __restrict__ m2b,   // 64x4096, 4096
    float* __restrict__ agg, int nE)
{
  __shared__ float s_hid[64][65];   // hidden[e][h]
  __shared__ float s_hvT[64][68];   // hv transposed: [i][e], row-aligned for float4
  __shared__ float s_bm[64][64];    // current B slice [i][o]
  __shared__ float s_m1w[16][64];
  __shared__ float s_m1b[64];
  __shared__ float s_ea[64][17];    // eattr[e][i]
  __shared__ int   s_srcn[64];
  __shared__ int   s_dst[64];

  int tid = threadIdx.x;
  int e0  = blockIdx.x * 64;

  for (int i = tid; i < 16 * 64; i += 256) s_m1w[i >> 6][i & 63] = m1w[i];
  if (tid < 64) s_m1b[tid] = m1b[tid];
  for (int idx = tid; idx < 64 * 16; idx += 256) {
    int e = idx >> 4, i = idx & 15, ge = e0 + e;
    s_ea[e][i] = (ge < nE) ? eattr[ge * 16 + i] : 0.0f;
  }
  if (tid < 64) {
    int ge = e0 + tid;
    s_srcn[tid] = (ge < nE) ? esrc[ge] : 0;
    s_dst[tid]  = (ge < nE) ? edst[ge] : -1;
  }
  __syncthreads();

  // gather source features (transposed) + compute hidden
  for (int idx = tid; idx < 4096; idx += 256) {
    int e = idx >> 6, i = idx & 63;
    s_hvT[i][e] = h_src[s_srcn[e] * 64 + i];
  }
  for (int idx = tid; idx < 4096; idx += 256) {
    int e = idx >> 6, o = idx & 63;
    float a = s_m1b[o];
    #pragma unroll
    for (int i = 0; i < 16; ++i) a = fmaf(s_ea[e][i], s_m1w[i][o], a);
    s_hid[e][o] = fmaxf(a, 0.0f);
  }

  float acc[4][4] = {};
  int rr4 = (tid >> 4) * 4;      // 4 edge-rows
  int cc4 = (tid & 15) * 4;      // 4 output-cols

  for (int h = 0; h < 65; ++h) {
    const float* bsrc = (h < 64) ? (m2w + h * 4096) : m2b;
    __syncthreads();
    for (int idx = tid; idx < 4096; idx += 256) s_bm[idx >> 6][idx & 63] = bsrc[idx];
    __syncthreads();

    float ah0, ah1, ah2, ah3;
    if (h < 64) {
      ah0 = s_hid[rr4 + 0][h]; ah1 = s_hid[rr4 + 1][h];
      ah2 = s_hid[rr4 + 2][h]; ah3 = s_hid[rr4 + 3][h];
    } else { ah0 = ah1 = ah2 = ah3 = 1.0f; }  // bias slice

    #pragma unroll 4
    for (int i = 0; i < 64; ++i) {
      const float4 av = *reinterpret_cast<const float4*>(&s_hvT[i][rr4]);
      const float4 bv = *reinterpret_cast<const float4*>(&s_bm[i][cc4]);
      float p0 = ah0 * av.x, p1 = ah1 * av.y, p2 = ah2 * av.z, p3 = ah3 * av.w;
      acc[0][0] = fmaf(p0, bv.x, acc[0][0]); acc[0][1] = fmaf(p0, bv.y, acc[0][1]);
      acc[0][2] = fmaf(p0, bv.z, acc[0][2]); acc[0][3] = fmaf(p0, bv.w, acc[0][3]);
      acc[1][0] = fmaf(p1, bv.x, acc[1][0]); acc[1][1] = fmaf(p1, bv.y, acc[1][1]);
      acc[1][2] = fmaf(p1, bv.z, acc[1][2]); acc[1][3] = fmaf(p1, bv.w, acc[1][3]);
      acc[2][0] = fmaf(p2, bv.x, acc[2][0]); acc[2][1] = fmaf(p2, bv.y, acc[2][1]);
      acc[2][2] = fmaf(p2, bv.z, acc[2][2]); acc[2][3] = fmaf(p2, bv.w, acc[2][3]);
      acc[3][0] = fmaf(p3, bv.x, acc[3][0]); acc[3][1] = fmaf(p3, bv.y, acc[3][1]);
      acc[3][2] = fmaf(p3, bv.z, acc[3][2]); acc[3][3] = fmaf(p3, bv.w, acc[3][3]);
    }
  }

  #pragma unroll
  for (int r = 0; r < 4; ++r) {
    int d = s_dst[rr4 + r];
    if (d >= 0) {
      #pragma unroll
      for (int c = 0; c < 4; ++c)
        atomicMaxF(&agg[d * 64 + cc4 + c], acc[r][c]);
    }
  }
}

// new_h = relu( fix(agg) + h_old @ rw + rb ),  fix: -inf -> 0
__global__ __launch_bounds__(256) void conv_finalize(
    const float* __restrict__ agg, const float* __restrict__ h_old,
    const float* __restrict__ rw, const float* __restrict__ rb,
    float* __restrict__ h_new, int n)
{
  __shared__ float s_w[64 * 64];
  __shared__ float s_b[64];
  int tid = threadIdx.x;
  for (int i = tid; i < 4096; i += 256) s_w[i] = rw[i];
  if (tid < 64) s_b[tid] = rb[tid];
  __syncthreads();
  int wave = tid >> 6, lane = tid & 63;
  int node = blockIdx.x * 4 + wave;
  if (node >= n) return;
  float v = h_old[node * 64 + lane];
  float acc = s_b[lane];
  #pragma unroll 8
  for (int i = 0; i < 64; ++i)
    acc = fmaf(__shfl(v, i, 64), s_w[i * 64 + lane], acc);
  float a = agg[node * 64 + lane];
  if (a == -INFINITY) a = 0.0f;
  h_new[node * 64 + lane] = fmaxf(a + acc, 0.0f);
}

// predictor head: one wave per label edge, 8 edges per wave
__global__ __launch_bounds__(256) void head_kernel(
    const float* __restrict__ h_c, const float* __restrict__ h_t,
    const int* __restrict__ lsrc, const int* __restrict__ ldst,
    const float* __restrict__ lattr,
    const float* __restrict__ w0, const float* __restrict__ b0,
    const float* __restrict__ w1, const float* __restrict__ b1,
    const float* __restrict__ w2, const float* __restrict__ b2,
    float* __restrict__ preds, float* __restrict__ logits, int n)
{
  __shared__ float s_w0[144 * 64];
  __shared__ float s_w1[64 * 64];
  __shared__ float s_b0[64], s_b1[64], s_w2[64];
  int tid = threadIdx.x;
  for (int i = tid; i < 144 * 64; i += 256) s_w0[i] = w0[i];
  for (int i = tid; i < 4096; i += 256) s_w1[i] = w1[i];
  if (tid < 64) { s_b0[tid] = b0[tid]; s_b1[tid] = b1[tid]; s_w2[tid] = w2[tid]; }
  __syncthreads();
  int wave = tid >> 6, lane = tid & 63;
  float b2v = b2[0];
  int base = blockIdx.x * 32 + wave * 8;
  for (int k = 0; k < 8; ++k) {
    int e = base + k;
    if (e >= n) break;
    float zc = h_c[lsrc[e] * 64 + lane];
    float zt = h_t[ldst[e] * 64 + lane];
    float za = (lane < 16) ? lattr[e * 16 + lane] : 0.0f;
    float acc = s_b0[lane];
    #pragma unroll 8
    for (int i = 0; i < 64; ++i)
      acc = fmaf(__shfl(zc, i, 64), s_w0[i * 64 + lane], acc);
    #pragma unroll 8
    for (int i = 0; i < 64; ++i)
      acc = fmaf(__shfl(zt, i, 64), s_w0[(64 + i) * 64 + lane], acc);
    #pragma unroll
    for (int i = 0; i < 16; ++i)
      acc = fmaf(__shfl(za, i, 64), s_w0[(128 + i) * 64 + lane], acc);
    float z1 = fmaxf(acc, 0.0f);
    float acc2 = s_b1[lane];
    #pragma unroll 8
    for (int i = 0; i < 64; ++i)
      acc2 = fmaf(__shfl(z1, i, 64), s_w1[i * 64 + lane], acc2);
    float z2 = fmaxf(acc2, 0.0f);
    float t = z2 * s_w2[lane];
    #pragma unroll
    for (int off = 32; off > 0; off >>= 1) t += __shfl_xor(t, off, 64);
    if (lane == 0) {
      float lg = t + b2v;
      logits[e] = lg;
      preds[e]  = 1.0f / (1.0f + expf(-lg));
    }
  }
}

extern "C" void kernel_launch(void* const* d_in, const int* in_sizes, int n_in,
                              void* d_out, int out_size, void* d_ws, size_t ws_size,
                              hipStream_t stream) {
  const int*   x_c      = (const int*)  d_in[0];
  const int*   x_t      = (const int*)  d_in[1];
  const int*   esrc_ct  = (const int*)  d_in[2];
  const int*   edst_ct  = (const int*)  d_in[3];
  const int*   esrc_tc  = (const int*)  d_in[4];
  const int*   edst_tc  = (const int*)  d_in[5];
  const int*   lbl_src  = (const int*)  d_in[6];
  const int*   lbl_dst  = (const int*)  d_in[7];
  const float* eattr_ct = (const float*)d_in[8];
  const float* eattr_tc = (const float*)d_in[9];
  const float* lbl_attr = (const float*)d_in[10];
  const float* emb_c    = (const float*)d_in[11];
  const float* emb_t    = (const float*)d_in[12];
  const float* ntl_c_w  = (const float*)d_in[13];
  const float* ntl_c_b  = (const float*)d_in[14];
  const float* ntl_t_w  = (const float*)d_in[15];
  const float* ntl_t_b  = (const float*)d_in[16];
  const float* m1w      = (const float*)d_in[17];  // (2,2,16,64)
  const float* m1b      = (const float*)d_in[18];  // (2,2,64)
  const float* m2w      = (const float*)d_in[19];  // (2,2,64,4096)
  const float* m2b      = (const float*)d_in[20];  // (2,2,4096)
  const float* rw       = (const float*)d_in[21];  // (2,2,64,64)
  const float* rb       = (const float*)d_in[22];  // (2,2,64)
  const float* ph_w0    = (const float*)d_in[23];
  const float* ph_b0    = (const float*)d_in[24];
  const float* ph_w1    = (const float*)d_in[25];
  const float* ph_b1    = (const float*)d_in[26];
  const float* ph_w2    = (const float*)d_in[27];
  const float* ph_b2    = (const float*)d_in[28];

  float* out = (float*)d_out;

  // workspace layout (floats)
  float* ws = (float*)d_ws;
  float* h_c0  = ws;                 // 5000*64
  float* h_c1  = h_c0 + NCN * 64;
  float* h_t0  = h_c1 + NCN * 64;    // 10000*64
  float* h_t1  = h_t0 + NTN * 64;
  float* agg_c = h_t1 + NTN * 64;    // 5000*64
  float* agg_t = agg_c + NCN * 64;   // 10000*64

  // node transforms
  node_transform<<<(NCN + 3) / 4, 256, 0, stream>>>(emb_c, x_c, ntl_c_w, ntl_c_b, h_c0, NCN);
  node_transform<<<(NTN + 3) / 4, 256, 0, stream>>>(emb_t, x_t, ntl_t_w, ntl_t_b, h_t0, NTN);

  float* hc_cur = h_c0; float* hc_nxt = h_c1;
  float* ht_cur = h_t0; float* ht_nxt = h_t1;
  const int eblocks = (NEDGE + 63) / 64;

  for (int l = 0; l < 2; ++l) {
    int p0 = l * 2 + 0;   // ct direction (writes to t)
    int p1 = l * 2 + 1;   // tc direction (writes to c)
    fill_neginf<<<(NTN * 64 + 255) / 256, 256, 0, stream>>>(agg_t, NTN * 64);
    fill_neginf<<<(NCN * 64 + 255) / 256, 256, 0, stream>>>(agg_c, NCN * 64);
    conv_msg<<<eblocks, 256, 0, stream>>>(
        hc_cur, esrc_ct, edst_ct, eattr_ct,
        m1w + p0 * 16 * 64, m1b + p0 * 64, m2w + p0 * 64 * 4096, m2b + p0 * 4096,
        agg_t, NEDGE);
    conv_msg<<<eblocks, 256, 0, stream>>>(
        ht_cur, esrc_tc, edst_tc, eattr_tc,
        m1w + p1 * 16 * 64, m1b + p1 * 64, m2w + p1 * 64 * 4096, m2b + p1 * 4096,
        agg_c, NEDGE);
    conv_finalize<<<(NTN + 3) / 4, 256, 0, stream>>>(
        agg_t, ht_cur, rw + p0 * 4096, rb + p0 * 64, ht_nxt, NTN);
    conv_finalize<<<(NCN + 3) / 4, 256, 0, stream>>>(
        agg_c, hc_cur, rw + p1 * 4096, rb + p1 * 64, hc_nxt, NCN);
    float* t;
    t = hc_cur; hc_cur = hc_nxt; hc_nxt = t;
    t = ht_cur; ht_cur = ht_nxt; ht_nxt = t;
  }

  head_kernel<<<(NLBL + 31) / 32, 256, 0, stream>>>(
      hc_cur, ht_cur, lbl_src, lbl_dst, lbl_attr,
      ph_w0, ph_b0, ph_w1, ph_b1, ph_w2, ph_b2,
      out, out + NLBL, NLBL);
}

// Round 2
// 462.366 us; speedup vs baseline: 5.3310x; 5.3310x over previous
//
#include <hip/hip_runtime.h>
#include <hip/hip_bf16.h>
#include <math.h>

// ---------------- problem constants ----------------
#define NCN   5000      // customer nodes
#define NTN   10000     // target nodes
#define NEDGE 50000     // edges per direction
#define NLBL  20000     // label edges
// EMB = OUT = 64, EF = 16, L = 2

typedef _Float16 f16x8 __attribute__((ext_vector_type(8)));
typedef _Float16 f16x4 __attribute__((ext_vector_type(4)));
typedef float    f32x4 __attribute__((ext_vector_type(4)));

#define HSTRIDE 264          // halves per hidT row (64 rows)
#define NSLICE  130          // 128 m2w K-slices + 2 bias slices

// float atomic max via int/uint monotonic reinterpretation
__device__ __forceinline__ void atomicMaxF(float* addr, float v) {
  if (v >= 0.0f) atomicMax((int*)addr, __float_as_int(v));
  else           atomicMin((unsigned int*)addr, __float_as_uint(v));
}

__device__ __forceinline__ void stage16(const _Float16* g, _Float16* l) {
  __builtin_amdgcn_global_load_lds(
      (const __attribute__((address_space(1))) void*)g,
      (__attribute__((address_space(3))) void*)l, 16, 0, 0);
}

__global__ __launch_bounds__(256) void fill_neginf(float* __restrict__ p, int n) {
  int i = blockIdx.x * 256 + threadIdx.x;
  if (i < n) p[i] = -INFINITY;
}

// ---- prep: m2w (+m2b) -> f16 slices in MFMA fragment order ----
// out[p][s][t*8+j]:  s<128: h=s>>1, i=(s&1)*32+hi*8+j, val=m2w[p][h*4096+i*64+col]
//                    s>=128: i=(s-128)*32+hi*8+j,      val=m2b[p][i*64+col]
__global__ __launch_bounds__(256) void prep_B(
    const float* __restrict__ m2w, const float* __restrict__ m2b,
    _Float16* __restrict__ out)
{
  int p = blockIdx.x / NSLICE;
  int s = blockIdx.x % NSLICE;
  int t = threadIdx.x;
  int hi = t >> 6, col = t & 63;
  const float* w  = m2w + p * 64 * 4096;
  const float* bb = m2b + p * 4096;
  f16x8 v;
  #pragma unroll
  for (int j = 0; j < 8; ++j) {
    float x;
    if (s < 128) {
      int h = s >> 1, i = (s & 1) * 32 + hi * 8 + j;
      x = w[h * 4096 + i * 64 + col];
    } else {
      int i = (s - 128) * 32 + hi * 8 + j;
      x = bb[i * 64 + col];
    }
    v[j] = (_Float16)x;
  }
  *(f16x8*)(out + ((size_t)(p * NSLICE + s)) * 2048 + t * 8) = v;
}

// m1 slice: i = hi*8+j; i<16 -> m1w, i==16 -> m1b (bias via A=1), else 0
__global__ __launch_bounds__(256) void prep_m1(
    const float* __restrict__ m1w, const float* __restrict__ m1b,
    _Float16* __restrict__ out)
{
  int p = blockIdx.x;
  int t = threadIdx.x;
  int hi = t >> 6, col = t & 63;
  f16x8 v;
  #pragma unroll
  for (int j = 0; j < 8; ++j) {
    int i = hi * 8 + j;
    float x = (i < 16) ? m1w[p * 1024 + i * 64 + col]
            : (i == 16) ? m1b[p * 64 + col] : 0.0f;
    v[j] = (_Float16)x;
  }
  *(f16x8*)(out + (size_t)p * 2048 + t * 8) = v;
}

// h[node] = emb[idx[node]] @ w(64x64) + b   (one wave per node)
__global__ __launch_bounds__(256) void node_transform(
    const float* __restrict__ emb, const int* __restrict__ idx,
    const float* __restrict__ w, const float* __restrict__ b,
    float* __restrict__ hout, int n)
{
  __shared__ float s_w[64 * 64];
  __shared__ float s_b[64];
  int tid = threadIdx.x;
  for (int i = tid; i < 4096; i += 256) s_w[i] = w[i];
  if (tid < 64) s_b[tid] = b[tid];
  __syncthreads();
  int wave = tid >> 6, lane = tid & 63;
  int node = blockIdx.x * 4 + wave;
  if (node >= n) return;
  float v = emb[idx[node] * 64 + lane];
  float acc = s_b[lane];
  #pragma unroll 8
  for (int i = 0; i < 64; ++i)
    acc = fmaf(__shfl(v, i, 64), s_w[i * 64 + lane], acc);
  hout[node * 64 + lane] = acc;
}

// ---- MFMA NNConv message pass: 256 edges/block, 4 waves, 64 edges/wave ----
__global__ __launch_bounds__(256) void conv_msg_mfma(
    const float* __restrict__ h_src,
    const int* __restrict__ esrc, const int* __restrict__ edst,
    const float* __restrict__ eattr,
    const _Float16* __restrict__ Bready,    // NSLICE*2048 halves for this conv
    const _Float16* __restrict__ m1ready,   // 2048 halves
    float* __restrict__ agg, int nE)
{
  __shared__ __align__(16) _Float16 s_B[2][2048];
  __shared__ __align__(16) _Float16 s_hidT[64 * HSTRIDE];
  __shared__ int s_srcn[256];
  __shared__ int s_dst[256];

  const int tid  = threadIdx.x;
  const int e0   = blockIdx.x * 256;
  const int w    = tid >> 6;
  const int lane = tid & 63;
  const int l15  = lane & 15;
  const int hi   = lane >> 4;
  const int w64  = w * 64;

  // stage m1 fragment block into s_B[0]
  stage16(m1ready + tid * 8, &s_B[0][tid * 8]);

  {
    int ge = e0 + tid;
    s_srcn[tid] = (ge < nE) ? esrc[ge] : 0;
    s_dst[tid]  = (ge < nE) ? edst[ge] : -1;
  }
  __syncthreads();   // m1 staged (vmcnt drain) + srcn/dst visible

  // ---- gather hv into registers (per M-tile, per i-set) ----
  f16x8 hv0[4], hv1[4];
  #pragma unroll
  for (int m = 0; m < 4; ++m) {
    int el = w64 + m * 16 + l15;
    const float* src = h_src + (size_t)s_srcn[el] * 64;
    float4 a0 = *(const float4*)(src + hi * 8);
    float4 a1 = *(const float4*)(src + hi * 8 + 4);
    float4 b0 = *(const float4*)(src + 32 + hi * 8);
    float4 b1 = *(const float4*)(src + 32 + hi * 8 + 4);
    hv0[m] = (f16x8){(_Float16)a0.x,(_Float16)a0.y,(_Float16)a0.z,(_Float16)a0.w,
                     (_Float16)a1.x,(_Float16)a1.y,(_Float16)a1.z,(_Float16)a1.w};
    hv1[m] = (f16x8){(_Float16)b0.x,(_Float16)b0.y,(_Float16)b0.z,(_Float16)b0.w,
                     (_Float16)b1.x,(_Float16)b1.y,(_Float16)b1.z,(_Float16)b1.w};
  }

  // ---- hidden = relu(eattr @ m1w + m1b) via one MFMA K-step ----
  {
    f16x8 ea[4];
    #pragma unroll
    for (int m = 0; m < 4; ++m) {
      int ge = e0 + w64 + m * 16 + l15;
      f16x8 v = {};
      if (hi < 2) {
        if (ge < nE) {
          float4 f0 = *(const float4*)(eattr + (size_t)ge * 16 + hi * 8);
          float4 f1 = *(const float4*)(eattr + (size_t)ge * 16 + hi * 8 + 4);
          v = (f16x8){(_Float16)f0.x,(_Float16)f0.y,(_Float16)f0.z,(_Float16)f0.w,
                      (_Float16)f1.x,(_Float16)f1.y,(_Float16)f1.z,(_Float16)f1.w};
        }
      } else if (hi == 2) {
        v[0] = (_Float16)1.0f;    // i==16 -> bias row
      }
      ea[m] = v;
    }
    f32x4 hacc[4][4] = {};
    #pragma unroll
    for (int n = 0; n < 4; ++n) {
      f16x8 bm = *(const f16x8*)&s_B[0][(hi * 64 + n * 16 + l15) * 8];
      #pragma unroll
      for (int m = 0; m < 4; ++m)
        hacc[m][n] = __builtin_amdgcn_mfma_f32_16x16x32_f16(ea[m], bm, hacc[m][n], 0, 0, 0);
    }
    __syncthreads();   // all waves done reading s_B[0]
    #pragma unroll
    for (int m = 0; m < 4; ++m) {
      #pragma unroll
      for (int n = 0; n < 4; ++n) {
        int h  = n * 16 + l15;
        int e4 = w64 + m * 16 + hi * 4;
        f16x4 hval;
        #pragma unroll
        for (int r = 0; r < 4; ++r) hval[r] = (_Float16)fmaxf(hacc[m][n][r], 0.0f);
        *(f16x4*)&s_hidT[h * HSTRIDE + e4] = hval;
      }
    }
  }

  // stage K-slice 0 into s_B[0] (drained at first KSTEP's syncthreads)
  stage16(Bready + tid * 8, &s_B[0][tid * 8]);

  f32x4 acc[4][4] = {};
  _Float16 hidh[4];

#define KSTEP(S, HVQ, READH, USEH)                                            \
  {                                                                           \
    __syncthreads();                                                          \
    if ((S) < NSLICE - 1)                                                     \
      stage16(Bready + (size_t)((S) + 1) * 2048 + tid * 8,                    \
              &s_B[((S) + 1) & 1][tid * 8]);                                  \
    const _Float16* bbuf = s_B[(S) & 1];                                      \
    f16x8 bfr0 = *(const f16x8*)&bbuf[(hi * 64 +  0 + l15) * 8];              \
    f16x8 bfr1 = *(const f16x8*)&bbuf[(hi * 64 + 16 + l15) * 8];              \
    f16x8 bfr2 = *(const f16x8*)&bbuf[(hi * 64 + 32 + l15) * 8];              \
    f16x8 bfr3 = *(const f16x8*)&bbuf[(hi * 64 + 48 + l15) * 8];              \
    if (READH) {                                                              \
      _Pragma("unroll")                                                       \
      for (int m = 0; m < 4; ++m)                                             \
        hidh[m] = s_hidT[((S) >> 1) * HSTRIDE + w64 + m * 16 + l15];          \
    }                                                                         \
    _Pragma("unroll")                                                         \
    for (int m = 0; m < 4; ++m) {                                             \
      f16x8 av = (USEH) ? (f16x8)(HVQ[m] * hidh[m]) : HVQ[m];                 \
      acc[m][0] = __builtin_amdgcn_mfma_f32_16x16x32_f16(av, bfr0, acc[m][0], 0, 0, 0); \
      acc[m][1] = __builtin_amdgcn_mfma_f32_16x16x32_f16(av, bfr1, acc[m][1], 0, 0, 0); \
      acc[m][2] = __builtin_amdgcn_mfma_f32_16x16x32_f16(av, bfr2, acc[m][2], 0, 0, 0); \
      acc[m][3] = __builtin_amdgcn_mfma_f32_16x16x32_f16(av, bfr3, acc[m][3], 0, 0, 0); \
    }                                                                         \
  }

  for (int s2 = 0; s2 < 64; ++s2) {
    KSTEP(2 * s2,     hv0, true,  true);
    KSTEP(2 * s2 + 1, hv1, false, true);
  }
  // bias slices: A = hv directly (hid == 1)
  KSTEP(128, hv0, false, false);
  KSTEP(129, hv1, false, false);
#undef KSTEP

  // ---- epilogue: scatter atomic max ----
  #pragma unroll
  for (int m = 0; m < 4; ++m) {
    int d0 = s_dst[w64 + m * 16 + hi * 4 + 0];
    int d1 = s_dst[w64 + m * 16 + hi * 4 + 1];
    int d2 = s_dst[w64 + m * 16 + hi * 4 + 2];
    int d3 = s_dst[w64 + m * 16 + hi * 4 + 3];
    #pragma unroll
    for (int n = 0; n < 4; ++n) {
      int o = n * 16 + l15;
      if (d0 >= 0) atomicMaxF(&agg[(size_t)d0 * 64 + o], acc[m][n][0]);
      if (d1 >= 0) atomicMaxF(&agg[(size_t)d1 * 64 + o], acc[m][n][1]);
      if (d2 >= 0) atomicMaxF(&agg[(size_t)d2 * 64 + o], acc[m][n][2]);
      if (d3 >= 0) atomicMaxF(&agg[(size_t)d3 * 64 + o], acc[m][n][3]);
    }
  }
}

// new_h = relu( fix(agg) + h_old @ rw + rb ),  fix: -inf -> 0
__global__ __launch_bounds__(256) void conv_finalize(
    const float* __restrict__ agg, const float* __restrict__ h_old,
    const float* __restrict__ rw, const float* __restrict__ rb,
    float* __restrict__ h_new, int n)
{
  __shared__ float s_w[64 * 64];
  __shared__ float s_b[64];
  int tid = threadIdx.x;
  for (int i = tid; i < 4096; i += 256) s_w[i] = rw[i];
  if (tid < 64) s_b[tid] = rb[tid];
  __syncthreads();
  int wave = tid >> 6, lane = tid & 63;
  int node = blockIdx.x * 4 + wave;
  if (node >= n) return;
  float v = h_old[node * 64 + lane];
  float acc = s_b[lane];
  #pragma unroll 8
  for (int i = 0; i < 64; ++i)
    acc = fmaf(__shfl(v, i, 64), s_w[i * 64 + lane], acc);
  float a = agg[node * 64 + lane];
  if (a == -INFINITY) a = 0.0f;
  h_new[node * 64 + lane] = fmaxf(a + acc, 0.0f);
}

// predictor head: one wave per label edge, 8 edges per wave
__global__ __launch_bounds__(256) void head_kernel(
    const float* __restrict__ h_c, const float* __restrict__ h_t,
    const int* __restrict__ lsrc, const int* __restrict__ ldst,
    const float* __restrict__ lattr,
    const float* __restrict__ w0, const float* __restrict__ b0,
    const float* __restrict__ w1, const float* __restrict__ b1,
    const float* __restrict__ w2, const float* __restrict__ b2,
    float* __restrict__ preds, float* __restrict__ logits, int n)
{
  __shared__ float s_w0[144 * 64];
  __shared__ float s_w1[64 * 64];
  __shared__ float s_b0[64], s_b1[64], s_w2[64];
  int tid = threadIdx.x;
  for (int i = tid; i < 144 * 64; i += 256) s_w0[i] = w0[i];
  for (int i = tid; i < 4096; i += 256) s_w1[i] = w1[i];
  if (tid < 64) { s_b0[tid] = b0[tid]; s_b1[tid] = b1[tid]; s_w2[tid] = w2[tid]; }
  __syncthreads();
  int wave = tid >> 6, lane = tid & 63;
  float b2v = b2[0];
  int base = blockIdx.x * 32 + wave * 8;
  for (int k = 0; k < 8; ++k) {
    int e = base + k;
    if (e >= n) break;
    float zc = h_c[lsrc[e] * 64 + lane];
    float zt = h_t[ldst[e] * 64 + lane];
    float za = (lane < 16) ? lattr[e * 16 + lane] : 0.0f;
    float acc = s_b0[lane];
    #pragma unroll 8
    for (int i = 0; i < 64; ++i)
      acc = fmaf(__shfl(zc, i, 64), s_w0[i * 64 + lane], acc);
    #pragma unroll 8
    for (int i = 0; i < 64; ++i)
      acc = fmaf(__shfl(zt, i, 64), s_w0[(64 + i) * 64 + lane], acc);
    #pragma unroll
    for (int i = 0; i < 16; ++i)
      acc = fmaf(__shfl(za, i, 64), s_w0[(128 + i) * 64 + lane], acc);
    float z1 = fmaxf(acc, 0.0f);
    float acc2 = s_b1[lane];
    #pragma unroll 8
    for (int i = 0; i < 64; ++i)
      acc2 = fmaf(__shfl(z1, i, 64), s_w1[i * 64 + lane], acc2);
    float z2 = fmaxf(acc2, 0.0f);
    float t = z2 * s_w2[lane];
    #pragma unroll
    for (int off = 32; off > 0; off >>= 1) t += __shfl_xor(t, off, 64);
    if (lane == 0) {
      float lg = t + b2v;
      logits[e] = lg;
      preds[e]  = 1.0f / (1.0f + expf(-lg));
    }
  }
}

extern "C" void kernel_launch(void* const* d_in, const int* in_sizes, int n_in,
                              void* d_out, int out_size, void* d_ws, size_t ws_size,
                              hipStream_t stream) {
  const int*   x_c      = (const int*)  d_in[0];
  const int*   x_t      = (const int*)  d_in[1];
  const int*   esrc_ct  = (const int*)  d_in[2];
  const int*   edst_ct  = (const int*)  d_in[3];
  const int*   esrc_tc  = (const int*)  d_in[4];
  const int*   edst_tc  = (const int*)  d_in[5];
  const int*   lbl_src  = (const int*)  d_in[6];
  const int*   lbl_dst  = (const int*)  d_in[7];
  const float* eattr_ct = (const float*)d_in[8];
  const float* eattr_tc = (const float*)d_in[9];
  const float* lbl_attr = (const float*)d_in[10];
  const float* emb_c    = (const float*)d_in[11];
  const float* emb_t    = (const float*)d_in[12];
  const float* ntl_c_w  = (const float*)d_in[13];
  const float* ntl_c_b  = (const float*)d_in[14];
  const float* ntl_t_w  = (const float*)d_in[15];
  const float* ntl_t_b  = (const float*)d_in[16];
  const float* m1w      = (const float*)d_in[17];  // (2,2,16,64)
  const float* m1b      = (const float*)d_in[18];  // (2,2,64)
  const float* m2w      = (const float*)d_in[19];  // (2,2,64,4096)
  const float* m2b      = (const float*)d_in[20];  // (2,2,4096)
  const float* rw       = (const float*)d_in[21];  // (2,2,64,64)
  const float* rb       = (const float*)d_in[22];  // (2,2,64)
  const float* ph_w0    = (const float*)d_in[23];
  const float* ph_b0    = (const float*)d_in[24];
  const float* ph_w1    = (const float*)d_in[25];
  const float* ph_b1    = (const float*)d_in[26];
  const float* ph_w2    = (const float*)d_in[27];
  const float* ph_b2    = (const float*)d_in[28];

  float* out = (float*)d_out;

  // workspace layout
  float* ws = (float*)d_ws;
  float* h_c0  = ws;                 // 5000*64
  float* h_c1  = h_c0 + NCN * 64;
  float* h_t0  = h_c1 + NCN * 64;    // 10000*64
  float* h_t1  = h_t0 + NTN * 64;
  float* agg_c = h_t1 + NTN * 64;    // 5000*64
  float* agg_t = agg_c + NCN * 64;   // 10000*64
  _Float16* Bready  = (_Float16*)(agg_t + NTN * 64);   // 4*130*2048 halves
  _Float16* m1ready = Bready + 4 * NSLICE * 2048;      // 4*2048 halves

  // weight prep (cheap; deterministic each call)
  prep_B <<<4 * NSLICE, 256, 0, stream>>>(m2w, m2b, Bready);
  prep_m1<<<4, 256, 0, stream>>>(m1w, m1b, m1ready);

  // node transforms
  node_transform<<<(NCN + 3) / 4, 256, 0, stream>>>(emb_c, x_c, ntl_c_w, ntl_c_b, h_c0, NCN);
  node_transform<<<(NTN + 3) / 4, 256, 0, stream>>>(emb_t, x_t, ntl_t_w, ntl_t_b, h_t0, NTN);

  float* hc_cur = h_c0; float* hc_nxt = h_c1;
  float* ht_cur = h_t0; float* ht_nxt = h_t1;
  const int eblocks = (NEDGE + 255) / 256;

  for (int l = 0; l < 2; ++l) {
    int p0 = l * 2 + 0;   // ct direction (writes to t)
    int p1 = l * 2 + 1;   // tc direction (writes to c)
    fill_neginf<<<(NTN * 64 + 255) / 256, 256, 0, stream>>>(agg_t, NTN * 64);
    fill_neginf<<<(NCN * 64 + 255) / 256, 256, 0, stream>>>(agg_c, NCN * 64);
    conv_msg_mfma<<<eblocks, 256, 0, stream>>>(
        hc_cur, esrc_ct, edst_ct, eattr_ct,
        Bready + (size_t)p0 * NSLICE * 2048, m1ready + (size_t)p0 * 2048,
        agg_t, NEDGE);
    conv_msg_mfma<<<eblocks, 256, 0, stream>>>(
        ht_cur, esrc_tc, edst_tc, eattr_tc,
        Bready + (size_t)p1 * NSLICE * 2048, m1ready + (size_t)p1 * 2048,
        agg_c, NEDGE);
    conv_finalize<<<(NTN + 3) / 4, 256, 0, stream>>>(
        agg_t, ht_cur, rw + p0 * 4096, rb + p0 * 64, ht_nxt, NTN);
    conv_finalize<<<(NCN + 3) / 4, 256, 0, stream>>>(
        agg_c, hc_cur, rw + p1 * 4096, rb + p1 * 64, hc_nxt, NCN);
    float* t;
    t = hc_cur; hc_cur = hc_nxt; hc_nxt = t;
    t = ht_cur; ht_cur = ht_nxt; ht_nxt = t;
  }

  head_kernel<<<(NLBL + 31) / 32, 256, 0, stream>>>(
      hc_cur, ht_cur, lbl_src, lbl_dst, lbl_attr,
      ph_w0, ph_b0, ph_w1, ph_b1, ph_w2, ph_b2,
      out, out + NLBL, NLBL);
}

// Round 3
// 343.615 us; speedup vs baseline: 7.1734x; 1.3456x over previous
//
#include <hip/hip_runtime.h>
#include <hip/hip_bf16.h>
#include <math.h>

// ---------------- problem constants ----------------
#define NCN   5000      // customer nodes
#define NTN   10000     // target nodes
#define NEDGE 50000     // edges per direction
#define NLBL  20000     // label edges
// EMB = OUT = 64, EF = 16, L = 2

typedef _Float16 f16x8 __attribute__((ext_vector_type(8)));
typedef _Float16 f16x4 __attribute__((ext_vector_type(4)));
typedef float    f32x4 __attribute__((ext_vector_type(4)));

#define HSTRIDE 264          // halves per hidT row (256 edges + pad)
#define NSLICE  130          // 128 m2w K-slices + 2 bias slices
#define ZSTR    72           // head z-buffer stride in halves (144B, 16B-aligned rows)

// float atomic max via int/uint monotonic reinterpretation
__device__ __forceinline__ void atomicMaxF(float* addr, float v) {
  if (v >= 0.0f) atomicMax((int*)addr, __float_as_int(v));
  else           atomicMin((unsigned int*)addr, __float_as_uint(v));
}

__device__ __forceinline__ void stage16(const _Float16* g, _Float16* l) {
  __builtin_amdgcn_global_load_lds(
      (const __attribute__((address_space(1))) void*)g,
      (__attribute__((address_space(3))) void*)l, 16, 0, 0);
}

__global__ __launch_bounds__(256) void fill_neginf(float* __restrict__ p, int n) {
  int i = blockIdx.x * 256 + threadIdx.x;
  if (i < n) p[i] = -INFINITY;
}

// ---- prep: m2w (+m2b) -> f16 slices in MFMA fragment order ----
__global__ __launch_bounds__(256) void prep_B(
    const float* __restrict__ m2w, const float* __restrict__ m2b,
    _Float16* __restrict__ out)
{
  int p = blockIdx.x / NSLICE;
  int s = blockIdx.x % NSLICE;
  int t = threadIdx.x;
  int hi = t >> 6, col = t & 63;
  const float* w  = m2w + p * 64 * 4096;
  const float* bb = m2b + p * 4096;
  f16x8 v;
  #pragma unroll
  for (int j = 0; j < 8; ++j) {
    float x;
    if (s < 128) {
      int h = s >> 1, i = (s & 1) * 32 + hi * 8 + j;
      x = w[h * 4096 + i * 64 + col];
    } else {
      int i = (s - 128) * 32 + hi * 8 + j;
      x = bb[i * 64 + col];
    }
    v[j] = (_Float16)x;
  }
  *(f16x8*)(out + ((size_t)(p * NSLICE + s)) * 2048 + t * 8) = v;
}

// m1 slice: i = hi*8+j; i<16 -> m1w, i==16 -> m1b (bias via A=1), else 0
__global__ __launch_bounds__(256) void prep_m1(
    const float* __restrict__ m1w, const float* __restrict__ m1b,
    _Float16* __restrict__ out)
{
  int p = blockIdx.x;
  int t = threadIdx.x;
  int hi = t >> 6, col = t & 63;
  f16x8 v;
  #pragma unroll
  for (int j = 0; j < 8; ++j) {
    int i = hi * 8 + j;
    float x = (i < 16) ? m1w[p * 1024 + i * 64 + col]
            : (i == 16) ? m1b[p * 64 + col] : 0.0f;
    v[j] = (_Float16)x;
  }
  *(f16x8*)(out + (size_t)p * 2048 + t * 8) = v;
}

// head weights -> 8 f16 fragment slices:
//  s=0..4: layer1, krow = s*32+k: <144 -> w0[krow][col], ==144 -> b0[col], else 0
//  s=5..7: layer2, krow = (s-5)*32+k: <64 -> w1[krow][col], ==64 -> b1[col], else 0
__global__ __launch_bounds__(256) void prep_headB(
    const float* __restrict__ w0, const float* __restrict__ b0,
    const float* __restrict__ w1, const float* __restrict__ b1,
    _Float16* __restrict__ out)
{
  int s = blockIdx.x;
  int t = threadIdx.x;
  int hi = t >> 6, col = t & 63;
  f16x8 v;
  #pragma unroll
  for (int j = 0; j < 8; ++j) {
    int k = hi * 8 + j;
    float x = 0.0f;
    if (s < 5) {
      int kr = s * 32 + k;
      x = (kr < 144) ? w0[kr * 64 + col] : (kr == 144 ? b0[col] : 0.0f);
    } else {
      int kr = (s - 5) * 32 + k;
      x = (kr < 64) ? w1[kr * 64 + col] : (kr == 64 ? b1[col] : 0.0f);
    }
    v[j] = (_Float16)x;
  }
  *(f16x8*)(out + (size_t)s * 2048 + t * 8) = v;
}

// h[node] = emb[idx[node]] @ w(64x64) + b   (one wave per node)
__global__ __launch_bounds__(256) void node_transform(
    const float* __restrict__ emb, const int* __restrict__ idx,
    const float* __restrict__ w, const float* __restrict__ b,
    float* __restrict__ hout, int n)
{
  __shared__ float s_w[64 * 64];
  __shared__ float s_b[64];
  int tid = threadIdx.x;
  for (int i = tid; i < 4096; i += 256) s_w[i] = w[i];
  if (tid < 64) s_b[tid] = b[tid];
  __syncthreads();
  int wave = tid >> 6, lane = tid & 63;
  int node = blockIdx.x * 4 + wave;
  if (node >= n) return;
  float v = emb[idx[node] * 64 + lane];
  float acc = s_b[lane];
  #pragma unroll 8
  for (int i = 0; i < 64; ++i)
    acc = fmaf(__shfl(v, i, 64), s_w[i * 64 + lane], acc);
  hout[node * 64 + lane] = acc;
}

// ---- MFMA NNConv message pass: 256 edges/block, 4 waves, 64 edges/wave ----
// 65 phases x 2 K-slices, single raw barrier per phase; stage issued at phase
// top, vmcnt(0) at phase bottom -> stage latency hidden under 32 MFMA.
__global__ __launch_bounds__(256) void conv_msg_mfma(
    const float* __restrict__ h_src,
    const int* __restrict__ esrc, const int* __restrict__ edst,
    const float* __restrict__ eattr,
    const _Float16* __restrict__ Bready,    // NSLICE*2048 halves for this conv
    const _Float16* __restrict__ m1ready,   // 2048 halves
    float* __restrict__ agg, int nE)
{
  __shared__ __align__(16) _Float16 s_B[2][2][2048];   // [pair parity][slice in pair]
  __shared__ __align__(16) _Float16 s_m1f[2048];
  __shared__ __align__(16) _Float16 s_hidT[64 * HSTRIDE];
  __shared__ int s_srcn[256];
  __shared__ int s_dst[256];

  const int tid  = threadIdx.x;
  const int e0   = blockIdx.x * 256;
  const int w    = tid >> 6;
  const int lane = tid & 63;
  const int l15  = lane & 15;
  const int hi   = lane >> 4;
  const int w64  = w * 64;

  // prologue stages: m1 block + K-slices 0,1
  stage16(m1ready + tid * 8, &s_m1f[tid * 8]);
  stage16(Bready + tid * 8,        &s_B[0][0][tid * 8]);
  stage16(Bready + 2048 + tid * 8, &s_B[0][1][tid * 8]);

  {
    int ge = e0 + tid;
    s_srcn[tid] = (ge < nE) ? esrc[ge] : 0;
    s_dst[tid]  = (ge < nE) ? edst[ge] : -1;
  }
  __syncthreads();   // full drain: stages + idx visible

  // ---- gather hv into registers (per M-tile, per i-set) ----
  f16x8 hv0[4], hv1[4];
  #pragma unroll
  for (int m = 0; m < 4; ++m) {
    int el = w64 + m * 16 + l15;
    const float* src = h_src + (size_t)s_srcn[el] * 64;
    float4 a0 = *(const float4*)(src + hi * 8);
    float4 a1 = *(const float4*)(src + hi * 8 + 4);
    float4 b0 = *(const float4*)(src + 32 + hi * 8);
    float4 b1 = *(const float4*)(src + 32 + hi * 8 + 4);
    hv0[m] = (f16x8){(_Float16)a0.x,(_Float16)a0.y,(_Float16)a0.z,(_Float16)a0.w,
                     (_Float16)a1.x,(_Float16)a1.y,(_Float16)a1.z,(_Float16)a1.w};
    hv1[m] = (f16x8){(_Float16)b0.x,(_Float16)b0.y,(_Float16)b0.z,(_Float16)b0.w,
                     (_Float16)b1.x,(_Float16)b1.y,(_Float16)b1.z,(_Float16)b1.w};
  }

  // ---- hidden = relu(eattr @ m1w + m1b) via one MFMA K-step (from s_m1f) ----
  {
    f16x8 ea[4];
    #pragma unroll
    for (int m = 0; m < 4; ++m) {
      int ge = e0 + w64 + m * 16 + l15;
      f16x8 v = {};
      if (hi < 2) {
        if (ge < nE) {
          float4 f0 = *(const float4*)(eattr + (size_t)ge * 16 + hi * 8);
          float4 f1 = *(const float4*)(eattr + (size_t)ge * 16 + hi * 8 + 4);
          v = (f16x8){(_Float16)f0.x,(_Float16)f0.y,(_Float16)f0.z,(_Float16)f0.w,
                      (_Float16)f1.x,(_Float16)f1.y,(_Float16)f1.z,(_Float16)f1.w};
        }
      } else if (hi == 2) {
        v[0] = (_Float16)1.0f;    // i==16 -> bias row
      }
      ea[m] = v;
    }
    f32x4 hacc[4][4] = {};
    #pragma unroll
    for (int n = 0; n < 4; ++n) {
      f16x8 bm = *(const f16x8*)&s_m1f[(hi * 64 + n * 16 + l15) * 8];
      #pragma unroll
      for (int m = 0; m < 4; ++m)
        hacc[m][n] = __builtin_amdgcn_mfma_f32_16x16x32_f16(ea[m], bm, hacc[m][n], 0, 0, 0);
    }
    // hidT is wave-private (own 64-edge column block): no barrier needed
    #pragma unroll
    for (int m = 0; m < 4; ++m) {
      #pragma unroll
      for (int n = 0; n < 4; ++n) {
        int h  = n * 16 + l15;
        int e4 = w64 + m * 16 + hi * 4;
        f16x4 hval;
        #pragma unroll
        for (int r = 0; r < 4; ++r) hval[r] = (_Float16)fmaxf(hacc[m][n][r], 0.0f);
        *(f16x4*)&s_hidT[h * HSTRIDE + e4] = hval;
      }
    }
  }

  f32x4 acc[4][4] = {};

  // ---- phase loop: p=0..64, slices {2p, 2p+1} ----
  #pragma unroll 2
  for (int p = 0; p < 65; ++p) {
    const int P = p & 1;
    if (p < 64) {
      stage16(Bready + (size_t)(2 * p + 2) * 2048 + tid * 8, &s_B[P ^ 1][0][tid * 8]);
      stage16(Bready + (size_t)(2 * p + 3) * 2048 + tid * 8, &s_B[P ^ 1][1][tid * 8]);
    }
    f16x8 bf0[4], bf1[4];
    #pragma unroll
    for (int n = 0; n < 4; ++n) {
      bf0[n] = *(const f16x8*)&s_B[P][0][(hi * 64 + n * 16 + l15) * 8];
      bf1[n] = *(const f16x8*)&s_B[P][1][(hi * 64 + n * 16 + l15) * 8];
    }
    _Float16 hidh[4];
    if (p < 64) {
      #pragma unroll
      for (int m = 0; m < 4; ++m)
        hidh[m] = s_hidT[p * HSTRIDE + w64 + m * 16 + l15];
    }
    #pragma unroll
    for (int m = 0; m < 4; ++m) {
      f16x8 av0 = (p < 64) ? (f16x8)(hv0[m] * hidh[m]) : hv0[m];
      #pragma unroll
      for (int n = 0; n < 4; ++n)
        acc[m][n] = __builtin_amdgcn_mfma_f32_16x16x32_f16(av0, bf0[n], acc[m][n], 0, 0, 0);
    }
    #pragma unroll
    for (int m = 0; m < 4; ++m) {
      f16x8 av1 = (p < 64) ? (f16x8)(hv1[m] * hidh[m]) : hv1[m];
      #pragma unroll
      for (int n = 0; n < 4; ++n)
        acc[m][n] = __builtin_amdgcn_mfma_f32_16x16x32_f16(av1, bf1[n], acc[m][n], 0, 0, 0);
    }
    asm volatile("s_waitcnt vmcnt(0)" ::: "memory");  // our 2 stages (issued ~700cy ago) done
    __builtin_amdgcn_s_barrier();                      // all waves: reads done + stages landed
  }

  // ---- epilogue: scatter atomic max ----
  #pragma unroll
  for (int m = 0; m < 4; ++m) {
    int d0 = s_dst[w64 + m * 16 + hi * 4 + 0];
    int d1 = s_dst[w64 + m * 16 + hi * 4 + 1];
    int d2 = s_dst[w64 + m * 16 + hi * 4 + 2];
    int d3 = s_dst[w64 + m * 16 + hi * 4 + 3];
    #pragma unroll
    for (int n = 0; n < 4; ++n) {
      int o = n * 16 + l15;
      if (d0 >= 0) atomicMaxF(&agg[(size_t)d0 * 64 + o], acc[m][n][0]);
      if (d1 >= 0) atomicMaxF(&agg[(size_t)d1 * 64 + o], acc[m][n][1]);
      if (d2 >= 0) atomicMaxF(&agg[(size_t)d2 * 64 + o], acc[m][n][2]);
      if (d3 >= 0) atomicMaxF(&agg[(size_t)d3 * 64 + o], acc[m][n][3]);
    }
  }
}

// new_h = relu( fix(agg) + h_old @ rw + rb ),  fix: -inf -> 0
// Also re-initializes agg to -inf for the next conv layer (saves fill dispatches).
__global__ __launch_bounds__(256) void conv_finalize(
    float* __restrict__ agg, const float* __restrict__ h_old,
    const float* __restrict__ rw, const float* __restrict__ rb,
    float* __restrict__ h_new, int n)
{
  __shared__ float s_w[64 * 64];
  __shared__ float s_b[64];
  int tid = threadIdx.x;
  for (int i = tid; i < 4096; i += 256) s_w[i] = rw[i];
  if (tid < 64) s_b[tid] = rb[tid];
  __syncthreads();
  int wave = tid >> 6, lane = tid & 63;
  int node = blockIdx.x * 4 + wave;
  if (node >= n) return;
  float v = h_old[node * 64 + lane];
  float acc = s_b[lane];
  #pragma unroll 8
  for (int i = 0; i < 64; ++i)
    acc = fmaf(__shfl(v, i, 64), s_w[i * 64 + lane], acc);
  float a = agg[node * 64 + lane];
  agg[node * 64 + lane] = -INFINITY;   // re-init for next layer's atomics
  if (a == -INFINITY) a = 0.0f;
  h_new[node * 64 + lane] = fmaxf(a + acc, 0.0f);
}

// ---- MFMA predictor head: 128 edges/block (4 waves x 32 edges) ----
__global__ __launch_bounds__(256) void head_mfma(
    const float* __restrict__ h_c, const float* __restrict__ h_t,
    const int* __restrict__ lsrc, const int* __restrict__ ldst,
    const float* __restrict__ lattr,
    const _Float16* __restrict__ headB,   // 8*2048 halves
    const float* __restrict__ w2, const float* __restrict__ b2,
    float* __restrict__ preds, float* __restrict__ logits, int nL)
{
  __shared__ __align__(16) _Float16 s_W[8][2048];     // 32KB
  __shared__ __align__(16) _Float16 s_z[4][32][ZSTR]; // 18.4KB, wave-private rows
  __shared__ float s_w2[64];

  const int tid = threadIdx.x;
  const int wv = tid >> 6, lane = tid & 63;
  const int l15 = lane & 15, hi = lane >> 4;

  #pragma unroll
  for (int s = 0; s < 8; ++s)
    stage16(headB + s * 2048 + tid * 8, &s_W[s][tid * 8]);
  if (tid < 64) s_w2[tid] = w2[tid];
  const float b2v = b2[0];

  const int e0 = blockIdx.x * 128 + wv * 32;

  // gather layer-1 A-fragments (lane l15 = edge row, k = hi*8+j)
  f16x8 ac[2][2], at[2][2], aa[2];
  #pragma unroll
  for (int m = 0; m < 2; ++m) {
    int e = e0 + m * 16 + l15;
    int ee = (e < nL) ? e : 0;
    const float* pc = h_c + (size_t)lsrc[ee] * 64;
    const float* pt = h_t + (size_t)ldst[ee] * 64;
    #pragma unroll
    for (int half = 0; half < 2; ++half) {
      float4 c0 = *(const float4*)(pc + half * 32 + hi * 8);
      float4 c1 = *(const float4*)(pc + half * 32 + hi * 8 + 4);
      float4 t0 = *(const float4*)(pt + half * 32 + hi * 8);
      float4 t1 = *(const float4*)(pt + half * 32 + hi * 8 + 4);
      ac[m][half] = (f16x8){(_Float16)c0.x,(_Float16)c0.y,(_Float16)c0.z,(_Float16)c0.w,
                            (_Float16)c1.x,(_Float16)c1.y,(_Float16)c1.z,(_Float16)c1.w};
      at[m][half] = (f16x8){(_Float16)t0.x,(_Float16)t0.y,(_Float16)t0.z,(_Float16)t0.w,
                            (_Float16)t1.x,(_Float16)t1.y,(_Float16)t1.z,(_Float16)t1.w};
    }
    f16x8 v = {};
    if (hi < 2) {
      float4 f0 = *(const float4*)(lattr + (size_t)ee * 16 + hi * 8);
      float4 f1 = *(const float4*)(lattr + (size_t)ee * 16 + hi * 8 + 4);
      v = (f16x8){(_Float16)f0.x,(_Float16)f0.y,(_Float16)f0.z,(_Float16)f0.w,
                  (_Float16)f1.x,(_Float16)f1.y,(_Float16)f1.z,(_Float16)f1.w};
    } else if (hi == 2) {
      v[0] = (_Float16)1.0f;   // krow 144 = bias
    }
    aa[m] = v;
  }

  __syncthreads();   // weights staged

  // ---- layer 1: 5 K-slices ----
  f32x4 acc1[2][4] = {};
  #pragma unroll
  for (int s = 0; s < 5; ++s) {
    f16x8 bfr[4];
    #pragma unroll
    for (int nn = 0; nn < 4; ++nn)
      bfr[nn] = *(const f16x8*)&s_W[s][(hi * 64 + nn * 16 + l15) * 8];
    #pragma unroll
    for (int m = 0; m < 2; ++m) {
      f16x8 a = (s == 0) ? ac[m][0] : (s == 1) ? ac[m][1]
              : (s == 2) ? at[m][0] : (s == 3) ? at[m][1] : aa[m];
      #pragma unroll
      for (int nn = 0; nn < 4; ++nn)
        acc1[m][nn] = __builtin_amdgcn_mfma_f32_16x16x32_f16(a, bfr[nn], acc1[m][nn], 0, 0, 0);
    }
  }

  // relu + transpose to LDS (wave-private rows): row = edge-in-wave, col = feature
  #pragma unroll
  for (int m = 0; m < 2; ++m)
    #pragma unroll
    for (int nn = 0; nn < 4; ++nn)
      #pragma unroll
      for (int r = 0; r < 4; ++r)
        s_z[wv][m * 16 + hi * 4 + r][nn * 16 + l15] =
            (_Float16)fmaxf(acc1[m][nn][r], 0.0f);

  // ---- layer 2: 2 z-slices + bias slice ----
  f16x8 abias = {};
  if (hi == 0) abias[0] = (_Float16)1.0f;   // krow2 64 = bias
  f32x4 acc2[2][4] = {};
  #pragma unroll
  for (int s = 0; s < 3; ++s) {
    f16x8 bfr[4];
    #pragma unroll
    for (int nn = 0; nn < 4; ++nn)
      bfr[nn] = *(const f16x8*)&s_W[5 + s][(hi * 64 + nn * 16 + l15) * 8];
    #pragma unroll
    for (int m = 0; m < 2; ++m) {
      f16x8 a = (s < 2) ? *(const f16x8*)&s_z[wv][m * 16 + l15][s * 32 + hi * 8] : abias;
      #pragma unroll
      for (int nn = 0; nn < 4; ++nn)
        acc2[m][nn] = __builtin_amdgcn_mfma_f32_16x16x32_f16(a, bfr[nn], acc2[m][nn], 0, 0, 0);
    }
  }

  // ---- layer 3: relu + per-edge dot with w2, reduce across 16 lanes ----
  #pragma unroll
  for (int m = 0; m < 2; ++m) {
    float part[4];
    #pragma unroll
    for (int r = 0; r < 4; ++r) {
      float p = 0.0f;
      #pragma unroll
      for (int nn = 0; nn < 4; ++nn)
        p = fmaf(fmaxf(acc2[m][nn][r], 0.0f), s_w2[nn * 16 + l15], p);
      part[r] = p;
    }
    #pragma unroll
    for (int off = 1; off < 16; off <<= 1) {
      #pragma unroll
      for (int r = 0; r < 4; ++r)
        part[r] += __shfl_xor(part[r], off, 64);
    }
    if (l15 == 0) {
      #pragma unroll
      for (int r = 0; r < 4; ++r) {
        int e = e0 + m * 16 + hi * 4 + r;
        if (e < nL) {
          float lg = part[r] + b2v;
          logits[e] = lg;
          preds[e]  = 1.0f / (1.0f + expf(-lg));
        }
      }
    }
  }
}

extern "C" void kernel_launch(void* const* d_in, const int* in_sizes, int n_in,
                              void* d_out, int out_size, void* d_ws, size_t ws_size,
                              hipStream_t stream) {
  const int*   x_c      = (const int*)  d_in[0];
  const int*   x_t      = (const int*)  d_in[1];
  const int*   esrc_ct  = (const int*)  d_in[2];
  const int*   edst_ct  = (const int*)  d_in[3];
  const int*   esrc_tc  = (const int*)  d_in[4];
  const int*   edst_tc  = (const int*)  d_in[5];
  const int*   lbl_src  = (const int*)  d_in[6];
  const int*   lbl_dst  = (const int*)  d_in[7];
  const float* eattr_ct = (const float*)d_in[8];
  const float* eattr_tc = (const float*)d_in[9];
  const float* lbl_attr = (const float*)d_in[10];
  const float* emb_c    = (const float*)d_in[11];
  const float* emb_t    = (const float*)d_in[12];
  const float* ntl_c_w  = (const float*)d_in[13];
  const float* ntl_c_b  = (const float*)d_in[14];
  const float* ntl_t_w  = (const float*)d_in[15];
  const float* ntl_t_b  = (const float*)d_in[16];
  const float* m1w      = (const float*)d_in[17];  // (2,2,16,64)
  const float* m1b      = (const float*)d_in[18];  // (2,2,64)
  const float* m2w      = (const float*)d_in[19];  // (2,2,64,4096)
  const float* m2b      = (const float*)d_in[20];  // (2,2,4096)
  const float* rw       = (const float*)d_in[21];  // (2,2,64,64)
  const float* rb       = (const float*)d_in[22];  // (2,2,64)
  const float* ph_w0    = (const float*)d_in[23];
  const float* ph_b0    = (const float*)d_in[24];
  const float* ph_w1    = (const float*)d_in[25];
  const float* ph_b1    = (const float*)d_in[26];
  const float* ph_w2    = (const float*)d_in[27];
  const float* ph_b2    = (const float*)d_in[28];

  float* out = (float*)d_out;

  // workspace layout
  float* ws = (float*)d_ws;
  float* h_c0  = ws;                 // 5000*64
  float* h_c1  = h_c0 + NCN * 64;
  float* h_t0  = h_c1 + NCN * 64;    // 10000*64
  float* h_t1  = h_t0 + NTN * 64;
  float* agg_c = h_t1 + NTN * 64;    // 5000*64
  float* agg_t = agg_c + NCN * 64;   // 10000*64
  _Float16* Bready  = (_Float16*)(agg_t + NTN * 64);   // 4*130*2048 halves
  _Float16* m1ready = Bready + 4 * NSLICE * 2048;      // 4*2048 halves
  _Float16* headBr  = m1ready + 4 * 2048;              // 8*2048 halves

  // weight prep (cheap; deterministic each call)
  prep_B    <<<4 * NSLICE, 256, 0, stream>>>(m2w, m2b, Bready);
  prep_m1   <<<4, 256, 0, stream>>>(m1w, m1b, m1ready);
  prep_headB<<<8, 256, 0, stream>>>(ph_w0, ph_b0, ph_w1, ph_b1, headBr);

  // node transforms
  node_transform<<<(NCN + 3) / 4, 256, 0, stream>>>(emb_c, x_c, ntl_c_w, ntl_c_b, h_c0, NCN);
  node_transform<<<(NTN + 3) / 4, 256, 0, stream>>>(emb_t, x_t, ntl_t_w, ntl_t_b, h_t0, NTN);

  float* hc_cur = h_c0; float* hc_nxt = h_c1;
  float* ht_cur = h_t0; float* ht_nxt = h_t1;
  const int eblocks = (NEDGE + 255) / 256;

  for (int l = 0; l < 2; ++l) {
    int p0 = l * 2 + 0;   // ct direction (writes to t)
    int p1 = l * 2 + 1;   // tc direction (writes to c)
    if (l == 0) {
      fill_neginf<<<(NTN * 64 + 255) / 256, 256, 0, stream>>>(agg_t, NTN * 64);
      fill_neginf<<<(NCN * 64 + 255) / 256, 256, 0, stream>>>(agg_c, NCN * 64);
    }
    conv_msg_mfma<<<eblocks, 256, 0, stream>>>(
        hc_cur, esrc_ct, edst_ct, eattr_ct,
        Bready + (size_t)p0 * NSLICE * 2048, m1ready + (size_t)p0 * 2048,
        agg_t, NEDGE);
    conv_msg_mfma<<<eblocks, 256, 0, stream>>>(
        ht_cur, esrc_tc, edst_tc, eattr_tc,
        Bready + (size_t)p1 * NSLICE * 2048, m1ready + (size_t)p1 * 2048,
        agg_c, NEDGE);
    conv_finalize<<<(NTN + 3) / 4, 256, 0, stream>>>(
        agg_t, ht_cur, rw + p0 * 4096, rb + p0 * 64, ht_nxt, NTN);
    conv_finalize<<<(NCN + 3) / 4, 256, 0, stream>>>(
        agg_c, hc_cur, rw + p1 * 4096, rb + p1 * 64, hc_nxt, NCN);
    float* t;
    t = hc_cur; hc_cur = hc_nxt; hc_nxt = t;
    t = ht_cur; ht_cur = ht_nxt; ht_nxt = t;
  }

  head_mfma<<<(NLBL + 127) / 128, 256, 0, stream>>>(
      hc_cur, ht_cur, lbl_src, lbl_dst, lbl_attr,
      headBr, ph_w2, ph_b2,
      out, out + NLBL, NLBL);
}

// Round 4
// 249.561 us; speedup vs baseline: 9.8769x; 1.3769x over previous
//
#include <hip/hip_runtime.h>
#include <hip/hip_bf16.h>
#include <math.h>

// ---------------- problem constants ----------------
#define NCN   5000      // customer nodes
#define NTN   10000     // target nodes
#define NEDGE 50000     // edges per direction
#define NLBL  20000     // label edges
#define EBLK  196       // (NEDGE+255)/256 blocks per direction

typedef _Float16 f16x8 __attribute__((ext_vector_type(8)));
typedef _Float16 f16x4 __attribute__((ext_vector_type(4)));
typedef float    f32x4 __attribute__((ext_vector_type(4)));

#define HSTRIDE 264          // halves per hidT row (256 edges + pad)
#define NSLICE  130          // 128 m2w K-slices + 2 bias slices
#define ZSTR    72           // head z-buffer stride in halves

// float atomic max via int/uint monotonic reinterpretation
__device__ __forceinline__ void atomicMaxF(float* addr, float v) {
  if (v >= 0.0f) atomicMax((int*)addr, __float_as_int(v));
  else           atomicMin((unsigned int*)addr, __float_as_uint(v));
}

__device__ __forceinline__ void stage16(const _Float16* g, _Float16* l) {
  __builtin_amdgcn_global_load_lds(
      (const __attribute__((address_space(1))) void*)g,
      (__attribute__((address_space(3))) void*)l, 16, 0, 0);
}

__global__ __launch_bounds__(256) void fill_neginf(float* __restrict__ p, int n) {
  int i = blockIdx.x * 256 + threadIdx.x;
  if (i < n) p[i] = -INFINITY;
}

// ---- prep: m2w (+m2b) -> f16 slices in MFMA fragment order ----
__global__ __launch_bounds__(256) void prep_B(
    const float* __restrict__ m2w, const float* __restrict__ m2b,
    _Float16* __restrict__ out)
{
  int p = blockIdx.x / NSLICE;
  int s = blockIdx.x % NSLICE;
  int t = threadIdx.x;
  int hi = t >> 6, col = t & 63;
  const float* w  = m2w + p * 64 * 4096;
  const float* bb = m2b + p * 4096;
  f16x8 v;
  #pragma unroll
  for (int j = 0; j < 8; ++j) {
    float x;
    if (s < 128) {
      int h = s >> 1, i = (s & 1) * 32 + hi * 8 + j;
      x = w[h * 4096 + i * 64 + col];
    } else {
      int i = (s - 128) * 32 + hi * 8 + j;
      x = bb[i * 64 + col];
    }
    v[j] = (_Float16)x;
  }
  *(f16x8*)(out + ((size_t)(p * NSLICE + s)) * 2048 + t * 8) = v;
}

// m1 slice: i = hi*8+j; i<16 -> m1w, i==16 -> m1b (bias via A=1), else 0
__global__ __launch_bounds__(256) void prep_m1(
    const float* __restrict__ m1w, const float* __restrict__ m1b,
    _Float16* __restrict__ out)
{
  int p = blockIdx.x;
  int t = threadIdx.x;
  int hi = t >> 6, col = t & 63;
  f16x8 v;
  #pragma unroll
  for (int j = 0; j < 8; ++j) {
    int i = hi * 8 + j;
    float x = (i < 16) ? m1w[p * 1024 + i * 64 + col]
            : (i == 16) ? m1b[p * 64 + col] : 0.0f;
    v[j] = (_Float16)x;
  }
  *(f16x8*)(out + (size_t)p * 2048 + t * 8) = v;
}

// head weights -> 8 f16 fragment slices
__global__ __launch_bounds__(256) void prep_headB(
    const float* __restrict__ w0, const float* __restrict__ b0,
    const float* __restrict__ w1, const float* __restrict__ b1,
    _Float16* __restrict__ out)
{
  int s = blockIdx.x;
  int t = threadIdx.x;
  int hi = t >> 6, col = t & 63;
  f16x8 v;
  #pragma unroll
  for (int j = 0; j < 8; ++j) {
    int k = hi * 8 + j;
    float x = 0.0f;
    if (s < 5) {
      int kr = s * 32 + k;
      x = (kr < 144) ? w0[kr * 64 + col] : (kr == 144 ? b0[col] : 0.0f);
    } else {
      int kr = (s - 5) * 32 + k;
      x = (kr < 64) ? w1[kr * 64 + col] : (kr == 64 ? b1[col] : 0.0f);
    }
    v[j] = (_Float16)x;
  }
  *(f16x8*)(out + (size_t)s * 2048 + t * 8) = v;
}

// ---- merged node transform: dir0 = customer (blk0 blocks), dir1 = target ----
struct NtArgs {
  const float* emb0; const int* idx0; const float* w0; const float* b0; float* out0; int n0; int blk0;
  const float* emb1; const int* idx1; const float* w1; const float* b1; float* out1; int n1;
};

__global__ __launch_bounds__(256) void node_transform2(NtArgs a) {
  int bid = blockIdx.x;
  int dir = (bid >= a.blk0) ? 1 : 0;
  int lb  = bid - (dir ? a.blk0 : 0);
  const float* emb = dir ? a.emb1 : a.emb0;
  const int*   idx = dir ? a.idx1 : a.idx0;
  const float* w   = dir ? a.w1   : a.w0;
  const float* b   = dir ? a.b1   : a.b0;
  float*       out = dir ? a.out1 : a.out0;
  int          n   = dir ? a.n1   : a.n0;

  __shared__ float s_w[64 * 64];
  __shared__ float s_b[64];
  int tid = threadIdx.x;
  for (int i = tid; i < 4096; i += 256) s_w[i] = w[i];
  if (tid < 64) s_b[tid] = b[tid];
  __syncthreads();
  int wave = tid >> 6, lane = tid & 63;
  int node = lb * 4 + wave;
  if (node >= n) return;
  float v = emb[idx[node] * 64 + lane];
  float acc = s_b[lane];
  #pragma unroll 8
  for (int i = 0; i < 64; ++i)
    acc = fmaf(__shfl(v, i, 64), s_w[i * 64 + lane], acc);
  out[node * 64 + lane] = acc;
}

// ---- merged MFMA NNConv (both directions in one dispatch, grid = 2*EBLK) ----
// 33 phases x 4 K-slices (last phase = 2 bias slices), one barrier per phase.
struct ConvArgs {
  const float* h_src0; const int* esrc0; const int* edst0; const float* ea0;
  const _Float16* B0; const _Float16* m10; float* agg0;
  const float* h_src1; const int* esrc1; const int* edst1; const float* ea1;
  const _Float16* B1; const _Float16* m11; float* agg1;
};

__global__ __launch_bounds__(256) void conv_msg_mfma2(ConvArgs a) {
  __shared__ __align__(16) _Float16 s_B[2][4][2048];   // 32 KB, dbuf x 4 slices
  __shared__ __align__(16) _Float16 s_m1f[2048];
  __shared__ __align__(16) _Float16 s_hidT[64 * HSTRIDE];
  __shared__ int s_srcn[256];
  __shared__ int s_dst[256];

  const int bid = blockIdx.x;
  const int dir = (bid >= EBLK) ? 1 : 0;
  const int eb  = bid - (dir ? EBLK : 0);

  const float*    h_src  = dir ? a.h_src1 : a.h_src0;
  const int*      esrc   = dir ? a.esrc1  : a.esrc0;
  const int*      edst   = dir ? a.edst1  : a.edst0;
  const float*    eattr  = dir ? a.ea1    : a.ea0;
  const _Float16* Bready = dir ? a.B1     : a.B0;
  const _Float16* m1rdy  = dir ? a.m11    : a.m10;
  float*          agg    = dir ? a.agg1   : a.agg0;

  const int tid  = threadIdx.x;
  const int e0   = eb * 256;
  const int w    = tid >> 6;
  const int lane = tid & 63;
  const int l15  = lane & 15;
  const int hi   = lane >> 4;
  const int w64  = w * 64;

  // prologue stages: m1 block + K-slices 0..3
  stage16(m1rdy + tid * 8, &s_m1f[tid * 8]);
  #pragma unroll
  for (int q = 0; q < 4; ++q)
    stage16(Bready + (size_t)q * 2048 + tid * 8, &s_B[0][q][tid * 8]);

  {
    int ge = e0 + tid;
    s_srcn[tid] = (ge < NEDGE) ? esrc[ge] : 0;
    s_dst[tid]  = (ge < NEDGE) ? edst[ge] : -1;
  }
  __syncthreads();   // full drain: stages + idx visible

  // ---- gather hv into registers (per M-tile, per i-set) ----
  f16x8 hv0[4], hv1[4];
  #pragma unroll
  for (int m = 0; m < 4; ++m) {
    int el = w64 + m * 16 + l15;
    const float* src = h_src + (size_t)s_srcn[el] * 64;
    float4 a0 = *(const float4*)(src + hi * 8);
    float4 a1 = *(const float4*)(src + hi * 8 + 4);
    float4 b0 = *(const float4*)(src + 32 + hi * 8);
    float4 b1 = *(const float4*)(src + 32 + hi * 8 + 4);
    hv0[m] = (f16x8){(_Float16)a0.x,(_Float16)a0.y,(_Float16)a0.z,(_Float16)a0.w,
                     (_Float16)a1.x,(_Float16)a1.y,(_Float16)a1.z,(_Float16)a1.w};
    hv1[m] = (f16x8){(_Float16)b0.x,(_Float16)b0.y,(_Float16)b0.z,(_Float16)b0.w,
                     (_Float16)b1.x,(_Float16)b1.y,(_Float16)b1.z,(_Float16)b1.w};
  }

  // ---- hidden = relu(eattr @ m1w + m1b) via one MFMA K-step ----
  {
    f16x8 ea[4];
    #pragma unroll
    for (int m = 0; m < 4; ++m) {
      int ge = e0 + w64 + m * 16 + l15;
      f16x8 v = {};
      if (hi < 2) {
        if (ge < NEDGE) {
          float4 f0 = *(const float4*)(eattr + (size_t)ge * 16 + hi * 8);
          float4 f1 = *(const float4*)(eattr + (size_t)ge * 16 + hi * 8 + 4);
          v = (f16x8){(_Float16)f0.x,(_Float16)f0.y,(_Float16)f0.z,(_Float16)f0.w,
                      (_Float16)f1.x,(_Float16)f1.y,(_Float16)f1.z,(_Float16)f1.w};
        }
      } else if (hi == 2) {
        v[0] = (_Float16)1.0f;    // i==16 -> bias row
      }
      ea[m] = v;
    }
    f32x4 hacc[4][4] = {};
    #pragma unroll
    for (int n = 0; n < 4; ++n) {
      f16x8 bm = *(const f16x8*)&s_m1f[(hi * 64 + n * 16 + l15) * 8];
      #pragma unroll
      for (int m = 0; m < 4; ++m)
        hacc[m][n] = __builtin_amdgcn_mfma_f32_16x16x32_f16(ea[m], bm, hacc[m][n], 0, 0, 0);
    }
    // hidT rows are consumed only by the writing wave's edge block columns
    #pragma unroll
    for (int m = 0; m < 4; ++m) {
      #pragma unroll
      for (int n = 0; n < 4; ++n) {
        int h  = n * 16 + l15;
        int e4 = w64 + m * 16 + hi * 4;
        f16x4 hval;
        #pragma unroll
        for (int r = 0; r < 4; ++r) hval[r] = (_Float16)fmaxf(hacc[m][n][r], 0.0f);
        *(f16x4*)&s_hidT[h * HSTRIDE + e4] = hval;
      }
    }
  }

  f32x4 acc[4][4] = {};

#define MFMA_SLICE(P_, SS, HV, HH)                                            \
  {                                                                           \
    f16x8 b0 = *(const f16x8*)&s_B[P_][SS][(hi * 64 +  0 + l15) * 8];         \
    f16x8 b1 = *(const f16x8*)&s_B[P_][SS][(hi * 64 + 16 + l15) * 8];         \
    f16x8 b2 = *(const f16x8*)&s_B[P_][SS][(hi * 64 + 32 + l15) * 8];         \
    f16x8 b3 = *(const f16x8*)&s_B[P_][SS][(hi * 64 + 48 + l15) * 8];         \
    _Pragma("unroll")                                                         \
    for (int m = 0; m < 4; ++m) {                                             \
      f16x8 av = (f16x8)(HV[m] * HH[m]);                                      \
      acc[m][0] = __builtin_amdgcn_mfma_f32_16x16x32_f16(av, b0, acc[m][0], 0, 0, 0); \
      acc[m][1] = __builtin_amdgcn_mfma_f32_16x16x32_f16(av, b1, acc[m][1], 0, 0, 0); \
      acc[m][2] = __builtin_amdgcn_mfma_f32_16x16x32_f16(av, b2, acc[m][2], 0, 0, 0); \
      acc[m][3] = __builtin_amdgcn_mfma_f32_16x16x32_f16(av, b3, acc[m][3], 0, 0, 0); \
    }                                                                         \
  }

#define BIAS_SLICE(P_, SS, HV)                                                \
  {                                                                           \
    f16x8 b0 = *(const f16x8*)&s_B[P_][SS][(hi * 64 +  0 + l15) * 8];         \
    f16x8 b1 = *(const f16x8*)&s_B[P_][SS][(hi * 64 + 16 + l15) * 8];         \
    f16x8 b2 = *(const f16x8*)&s_B[P_][SS][(hi * 64 + 32 + l15) * 8];         \
    f16x8 b3 = *(const f16x8*)&s_B[P_][SS][(hi * 64 + 48 + l15) * 8];         \
    _Pragma("unroll")                                                         \
    for (int m = 0; m < 4; ++m) {                                             \
      f16x8 av = HV[m];                                                       \
      acc[m][0] = __builtin_amdgcn_mfma_f32_16x16x32_f16(av, b0, acc[m][0], 0, 0, 0); \
      acc[m][1] = __builtin_amdgcn_mfma_f32_16x16x32_f16(av, b1, acc[m][1], 0, 0, 0); \
      acc[m][2] = __builtin_amdgcn_mfma_f32_16x16x32_f16(av, b2, acc[m][2], 0, 0, 0); \
      acc[m][3] = __builtin_amdgcn_mfma_f32_16x16x32_f16(av, b3, acc[m][3], 0, 0, 0); \
    }                                                                         \
  }

  // ---- phase loop: p=0..31 full (4 slices), p=32 bias (2 slices) ----
  for (int p = 0; p < 33; ++p) {
    const int P = p & 1;
    if (p < 31) {
      #pragma unroll
      for (int q = 0; q < 4; ++q)
        stage16(Bready + (size_t)(4 * p + 4 + q) * 2048 + tid * 8,
                &s_B[P ^ 1][q][tid * 8]);
    } else if (p == 31) {
      stage16(Bready + (size_t)128 * 2048 + tid * 8, &s_B[P ^ 1][0][tid * 8]);
      stage16(Bready + (size_t)129 * 2048 + tid * 8, &s_B[P ^ 1][1][tid * 8]);
    }
    if (p < 32) {
      _Float16 hA[4], hB[4];
      #pragma unroll
      for (int m = 0; m < 4; ++m)
        hA[m] = s_hidT[(2 * p) * HSTRIDE + w64 + m * 16 + l15];
      #pragma unroll
      for (int m = 0; m < 4; ++m)
        hB[m] = s_hidT[(2 * p + 1) * HSTRIDE + w64 + m * 16 + l15];
      MFMA_SLICE(P, 0, hv0, hA);
      MFMA_SLICE(P, 1, hv1, hA);
      MFMA_SLICE(P, 2, hv0, hB);
      MFMA_SLICE(P, 3, hv1, hB);
    } else {
      BIAS_SLICE(P, 0, hv0);
      BIAS_SLICE(P, 1, hv1);
    }
    asm volatile("s_waitcnt vmcnt(0)" ::: "memory");
    __builtin_amdgcn_s_barrier();
  }
#undef MFMA_SLICE
#undef BIAS_SLICE

  // ---- epilogue: scatter atomic max ----
  #pragma unroll
  for (int m = 0; m < 4; ++m) {
    int d0 = s_dst[w64 + m * 16 + hi * 4 + 0];
    int d1 = s_dst[w64 + m * 16 + hi * 4 + 1];
    int d2 = s_dst[w64 + m * 16 + hi * 4 + 2];
    int d3 = s_dst[w64 + m * 16 + hi * 4 + 3];
    #pragma unroll
    for (int n = 0; n < 4; ++n) {
      int o = n * 16 + l15;
      if (d0 >= 0) atomicMaxF(&agg[(size_t)d0 * 64 + o], acc[m][n][0]);
      if (d1 >= 0) atomicMaxF(&agg[(size_t)d1 * 64 + o], acc[m][n][1]);
      if (d2 >= 0) atomicMaxF(&agg[(size_t)d2 * 64 + o], acc[m][n][2]);
      if (d3 >= 0) atomicMaxF(&agg[(size_t)d3 * 64 + o], acc[m][n][3]);
    }
  }
}

// ---- merged finalize: dir0 = target agg (blk0 blocks), dir1 = customer ----
struct FinArgs {
  float* agg0; const float* hold0; const float* rw0; const float* rb0; float* hnew0; int n0; int blk0;
  float* agg1; const float* hold1; const float* rw1; const float* rb1; float* hnew1; int n1;
};

__global__ __launch_bounds__(256) void conv_finalize2(FinArgs a) {
  int bid = blockIdx.x;
  int dir = (bid >= a.blk0) ? 1 : 0;
  int lb  = bid - (dir ? a.blk0 : 0);
  float*       agg  = dir ? a.agg1  : a.agg0;
  const float* hold = dir ? a.hold1 : a.hold0;
  const float* rw   = dir ? a.rw1   : a.rw0;
  const float* rb   = dir ? a.rb1   : a.rb0;
  float*       hnew = dir ? a.hnew1 : a.hnew0;
  int          n    = dir ? a.n1    : a.n0;

  __shared__ float s_w[64 * 64];
  __shared__ float s_b[64];
  int tid = threadIdx.x;
  for (int i = tid; i < 4096; i += 256) s_w[i] = rw[i];
  if (tid < 64) s_b[tid] = rb[tid];
  __syncthreads();
  int wave = tid >> 6, lane = tid & 63;
  int node = lb * 4 + wave;
  if (node >= n) return;
  float v = hold[node * 64 + lane];
  float acc = s_b[lane];
  #pragma unroll 8
  for (int i = 0; i < 64; ++i)
    acc = fmaf(__shfl(v, i, 64), s_w[i * 64 + lane], acc);
  float va = agg[node * 64 + lane];
  agg[node * 64 + lane] = -INFINITY;   // re-init for next layer's atomics
  if (va == -INFINITY) va = 0.0f;
  hnew[node * 64 + lane] = fmaxf(va + acc, 0.0f);
}

// ---- MFMA predictor head: 128 edges/block (4 waves x 32 edges) ----
__global__ __launch_bounds__(256) void head_mfma(
    const float* __restrict__ h_c, const float* __restrict__ h_t,
    const int* __restrict__ lsrc, const int* __restrict__ ldst,
    const float* __restrict__ lattr,
    const _Float16* __restrict__ headB,   // 8*2048 halves
    const float* __restrict__ w2, const float* __restrict__ b2,
    float* __restrict__ preds, float* __restrict__ logits, int nL)
{
  __shared__ __align__(16) _Float16 s_W[8][2048];     // 32KB
  __shared__ __align__(16) _Float16 s_z[4][32][ZSTR]; // 18.4KB, wave-private rows
  __shared__ float s_w2[64];

  const int tid = threadIdx.x;
  const int wv = tid >> 6, lane = tid & 63;
  const int l15 = lane & 15, hi = lane >> 4;

  #pragma unroll
  for (int s = 0; s < 8; ++s)
    stage16(headB + s * 2048 + tid * 8, &s_W[s][tid * 8]);
  if (tid < 64) s_w2[tid] = w2[tid];
  const float b2v = b2[0];

  const int e0 = blockIdx.x * 128 + wv * 32;

  // gather layer-1 A-fragments (lane l15 = edge row, k = hi*8+j)
  f16x8 ac[2][2], at[2][2], aa[2];
  #pragma unroll
  for (int m = 0; m < 2; ++m) {
    int e = e0 + m * 16 + l15;
    int ee = (e < nL) ? e : 0;
    const float* pc = h_c + (size_t)lsrc[ee] * 64;
    const float* pt = h_t + (size_t)ldst[ee] * 64;
    #pragma unroll
    for (int half = 0; half < 2; ++half) {
      float4 c0 = *(const float4*)(pc + half * 32 + hi * 8);
      float4 c1 = *(const float4*)(pc + half * 32 + hi * 8 + 4);
      float4 t0 = *(const float4*)(pt + half * 32 + hi * 8);
      float4 t1 = *(const float4*)(pt + half * 32 + hi * 8 + 4);
      ac[m][half] = (f16x8){(_Float16)c0.x,(_Float16)c0.y,(_Float16)c0.z,(_Float16)c0.w,
                            (_Float16)c1.x,(_Float16)c1.y,(_Float16)c1.z,(_Float16)c1.w};
      at[m][half] = (f16x8){(_Float16)t0.x,(_Float16)t0.y,(_Float16)t0.z,(_Float16)t0.w,
                            (_Float16)t1.x,(_Float16)t1.y,(_Float16)t1.z,(_Float16)t1.w};
    }
    f16x8 v = {};
    if (hi < 2) {
      float4 f0 = *(const float4*)(lattr + (size_t)ee * 16 + hi * 8);
      float4 f1 = *(const float4*)(lattr + (size_t)ee * 16 + hi * 8 + 4);
      v = (f16x8){(_Float16)f0.x,(_Float16)f0.y,(_Float16)f0.z,(_Float16)f0.w,
                  (_Float16)f1.x,(_Float16)f1.y,(_Float16)f1.z,(_Float16)f1.w};
    } else if (hi == 2) {
      v[0] = (_Float16)1.0f;   // krow 144 = bias
    }
    aa[m] = v;
  }

  __syncthreads();   // weights staged

  // ---- layer 1: 5 K-slices ----
  f32x4 acc1[2][4] = {};
  #pragma unroll
  for (int s = 0; s < 5; ++s) {
    f16x8 bfr[4];
    #pragma unroll
    for (int nn = 0; nn < 4; ++nn)
      bfr[nn] = *(const f16x8*)&s_W[s][(hi * 64 + nn * 16 + l15) * 8];
    #pragma unroll
    for (int m = 0; m < 2; ++m) {
      f16x8 a = (s == 0) ? ac[m][0] : (s == 1) ? ac[m][1]
              : (s == 2) ? at[m][0] : (s == 3) ? at[m][1] : aa[m];
      #pragma unroll
      for (int nn = 0; nn < 4; ++nn)
        acc1[m][nn] = __builtin_amdgcn_mfma_f32_16x16x32_f16(a, bfr[nn], acc1[m][nn], 0, 0, 0);
    }
  }

  // relu + transpose to LDS (wave-private rows)
  #pragma unroll
  for (int m = 0; m < 2; ++m)
    #pragma unroll
    for (int nn = 0; nn < 4; ++nn)
      #pragma unroll
      for (int r = 0; r < 4; ++r)
        s_z[wv][m * 16 + hi * 4 + r][nn * 16 + l15] =
            (_Float16)fmaxf(acc1[m][nn][r], 0.0f);

  // ---- layer 2: 2 z-slices + bias slice ----
  f16x8 abias = {};
  if (hi == 0) abias[0] = (_Float16)1.0f;   // krow2 64 = bias
  f32x4 acc2[2][4] = {};
  #pragma unroll
  for (int s = 0; s < 3; ++s) {
    f16x8 bfr[4];
    #pragma unroll
    for (int nn = 0; nn < 4; ++nn)
      bfr[nn] = *(const f16x8*)&s_W[5 + s][(hi * 64 + nn * 16 + l15) * 8];
    #pragma unroll
    for (int m = 0; m < 2; ++m) {
      f16x8 a = (s < 2) ? *(const f16x8*)&s_z[wv][m * 16 + l15][s * 32 + hi * 8] : abias;
      #pragma unroll
      for (int nn = 0; nn < 4; ++nn)
        acc2[m][nn] = __builtin_amdgcn_mfma_f32_16x16x32_f16(a, bfr[nn], acc2[m][nn], 0, 0, 0);
    }
  }

  // ---- layer 3: relu + per-edge dot with w2, reduce across 16 lanes ----
  #pragma unroll
  for (int m = 0; m < 2; ++m) {
    float part[4];
    #pragma unroll
    for (int r = 0; r < 4; ++r) {
      float p = 0.0f;
      #pragma unroll
      for (int nn = 0; nn < 4; ++nn)
        p = fmaf(fmaxf(acc2[m][nn][r], 0.0f), s_w2[nn * 16 + l15], p);
      part[r] = p;
    }
    #pragma unroll
    for (int off = 1; off < 16; off <<= 1) {
      #pragma unroll
      for (int r = 0; r < 4; ++r)
        part[r] += __shfl_xor(part[r], off, 64);
    }
    if (l15 == 0) {
      #pragma unroll
      for (int r = 0; r < 4; ++r) {
        int e = e0 + m * 16 + hi * 4 + r;
        if (e < nL) {
          float lg = part[r] + b2v;
          logits[e] = lg;
          preds[e]  = 1.0f / (1.0f + expf(-lg));
        }
      }
    }
  }
}

extern "C" void kernel_launch(void* const* d_in, const int* in_sizes, int n_in,
                              void* d_out, int out_size, void* d_ws, size_t ws_size,
                              hipStream_t stream) {
  const int*   x_c      = (const int*)  d_in[0];
  const int*   x_t      = (const int*)  d_in[1];
  const int*   esrc_ct  = (const int*)  d_in[2];
  const int*   edst_ct  = (const int*)  d_in[3];
  const int*   esrc_tc  = (const int*)  d_in[4];
  const int*   edst_tc  = (const int*)  d_in[5];
  const int*   lbl_src  = (const int*)  d_in[6];
  const int*   lbl_dst  = (const int*)  d_in[7];
  const float* eattr_ct = (const float*)d_in[8];
  const float* eattr_tc = (const float*)d_in[9];
  const float* lbl_attr = (const float*)d_in[10];
  const float* emb_c    = (const float*)d_in[11];
  const float* emb_t    = (const float*)d_in[12];
  const float* ntl_c_w  = (const float*)d_in[13];
  const float* ntl_c_b  = (const float*)d_in[14];
  const float* ntl_t_w  = (const float*)d_in[15];
  const float* ntl_t_b  = (const float*)d_in[16];
  const float* m1w      = (const float*)d_in[17];  // (2,2,16,64)
  const float* m1b      = (const float*)d_in[18];  // (2,2,64)
  const float* m2w      = (const float*)d_in[19];  // (2,2,64,4096)
  const float* m2b      = (const float*)d_in[20];  // (2,2,4096)
  const float* rw       = (const float*)d_in[21];  // (2,2,64,64)
  const float* rb       = (const float*)d_in[22];  // (2,2,64)
  const float* ph_w0    = (const float*)d_in[23];
  const float* ph_b0    = (const float*)d_in[24];
  const float* ph_w1    = (const float*)d_in[25];
  const float* ph_b1    = (const float*)d_in[26];
  const float* ph_w2    = (const float*)d_in[27];
  const float* ph_b2    = (const float*)d_in[28];

  float* out = (float*)d_out;

  // workspace layout
  float* ws = (float*)d_ws;
  float* h_c0  = ws;                 // 5000*64
  float* h_c1  = h_c0 + NCN * 64;
  float* h_t0  = h_c1 + NCN * 64;    // 10000*64
  float* h_t1  = h_t0 + NTN * 64;
  float* agg_c = h_t1 + NTN * 64;    // 5000*64
  float* agg_t = agg_c + NCN * 64;   // 10000*64 (contiguous after agg_c)
  _Float16* Bready  = (_Float16*)(agg_t + NTN * 64);   // 4*130*2048 halves
  _Float16* m1ready = Bready + 4 * NSLICE * 2048;      // 4*2048 halves
  _Float16* headBr  = m1ready + 4 * 2048;              // 8*2048 halves

  // weight prep
  prep_B    <<<4 * NSLICE, 256, 0, stream>>>(m2w, m2b, Bready);
  prep_m1   <<<4, 256, 0, stream>>>(m1w, m1b, m1ready);
  prep_headB<<<8, 256, 0, stream>>>(ph_w0, ph_b0, ph_w1, ph_b1, headBr);

  // merged node transforms (c: 1250 blocks, t: 2500 blocks)
  {
    NtArgs na;
    na.emb0 = emb_c; na.idx0 = x_c; na.w0 = ntl_c_w; na.b0 = ntl_c_b; na.out0 = h_c0; na.n0 = NCN;
    na.blk0 = (NCN + 3) / 4;
    na.emb1 = emb_t; na.idx1 = x_t; na.w1 = ntl_t_w; na.b1 = ntl_t_b; na.out1 = h_t0; na.n1 = NTN;
    node_transform2<<<(NCN + 3) / 4 + (NTN + 3) / 4, 256, 0, stream>>>(na);
  }

  // single merged fill (agg_c and agg_t contiguous)
  fill_neginf<<<((NCN + NTN) * 64 + 255) / 256, 256, 0, stream>>>(agg_c, (NCN + NTN) * 64);

  float* hc_cur = h_c0; float* hc_nxt = h_c1;
  float* ht_cur = h_t0; float* ht_nxt = h_t1;

  for (int l = 0; l < 2; ++l) {
    int p0 = l * 2 + 0;   // ct direction (writes to t)
    int p1 = l * 2 + 1;   // tc direction (writes to c)
    {
      ConvArgs ca;
      ca.h_src0 = hc_cur; ca.esrc0 = esrc_ct; ca.edst0 = edst_ct; ca.ea0 = eattr_ct;
      ca.B0 = Bready + (size_t)p0 * NSLICE * 2048; ca.m10 = m1ready + (size_t)p0 * 2048;
      ca.agg0 = agg_t;
      ca.h_src1 = ht_cur; ca.esrc1 = esrc_tc; ca.edst1 = edst_tc; ca.ea1 = eattr_tc;
      ca.B1 = Bready + (size_t)p1 * NSLICE * 2048; ca.m11 = m1ready + (size_t)p1 * 2048;
      ca.agg1 = agg_c;
      conv_msg_mfma2<<<2 * EBLK, 256, 0, stream>>>(ca);
    }
    {
      FinArgs fa;
      fa.agg0 = agg_t; fa.hold0 = ht_cur; fa.rw0 = rw + p0 * 4096; fa.rb0 = rb + p0 * 64;
      fa.hnew0 = ht_nxt; fa.n0 = NTN; fa.blk0 = (NTN + 3) / 4;
      fa.agg1 = agg_c; fa.hold1 = hc_cur; fa.rw1 = rw + p1 * 4096; fa.rb1 = rb + p1 * 64;
      fa.hnew1 = hc_nxt; fa.n1 = NCN;
      conv_finalize2<<<(NTN + 3) / 4 + (NCN + 3) / 4, 256, 0, stream>>>(fa);
    }
    float* t;
    t = hc_cur; hc_cur = hc_nxt; hc_nxt = t;
    t = ht_cur; ht_cur = ht_nxt; ht_nxt = t;
  }

  head_mfma<<<(NLBL + 127) / 128, 256, 0, stream>>>(
      hc_cur, ht_cur, lbl_src, lbl_dst, lbl_attr,
      headBr, ph_w2, ph_b2,
      out, out + NLBL, NLBL);
}

// Round 5
// 236.831 us; speedup vs baseline: 10.4078x; 1.0538x over previous
//
#include <hip/hip_runtime.h>
#include <hip/hip_bf16.h>
#include <math.h>

// ---------------- problem constants ----------------
#define NCN   5000      // customer nodes
#define NTN   10000     // target nodes
#define NEDGE 50000     // edges per direction
#define ESLOT 50176     // padded slots per direction (196 * 256)
#define NLBL  20000     // label edges
#define EBLK  196       // edge tiles per direction

typedef _Float16 f16x8 __attribute__((ext_vector_type(8)));
typedef _Float16 f16x4 __attribute__((ext_vector_type(4)));
typedef float    f32x4 __attribute__((ext_vector_type(4)));

#define HSTRIDE 264          // halves per hidT row (256 edges + pad)
#define NSLICE  130          // 128 m2w K-slices + 2 bias slices
#define ZSTR    72           // head z-buffer stride in halves

__device__ __forceinline__ void stage16(const _Float16* g, _Float16* l) {
  __builtin_amdgcn_global_load_lds(
      (const __attribute__((address_space(1))) void*)g,
      (__attribute__((address_space(3))) void*)l, 16, 0, 0);
}

// ---- prep: m2w (+m2b) -> f16 slices in MFMA fragment order ----
__global__ __launch_bounds__(256) void prep_B(
    const float* __restrict__ m2w, const float* __restrict__ m2b,
    _Float16* __restrict__ out)
{
  int p = blockIdx.x / NSLICE;
  int s = blockIdx.x % NSLICE;
  int t = threadIdx.x;
  int hi = t >> 6, col = t & 63;
  const float* w  = m2w + p * 64 * 4096;
  const float* bb = m2b + p * 4096;
  f16x8 v;
  #pragma unroll
  for (int j = 0; j < 8; ++j) {
    float x;
    if (s < 128) {
      int h = s >> 1, i = (s & 1) * 32 + hi * 8 + j;
      x = w[h * 4096 + i * 64 + col];
    } else {
      int i = (s - 128) * 32 + hi * 8 + j;
      x = bb[i * 64 + col];
    }
    v[j] = (_Float16)x;
  }
  *(f16x8*)(out + ((size_t)(p * NSLICE + s)) * 2048 + t * 8) = v;
}

// m1 slice: i = hi*8+j; i<16 -> m1w, i==16 -> m1b (bias via A=1), else 0
__global__ __launch_bounds__(256) void prep_m1(
    const float* __restrict__ m1w, const float* __restrict__ m1b,
    _Float16* __restrict__ out)
{
  int p = blockIdx.x;
  int t = threadIdx.x;
  int hi = t >> 6, col = t & 63;
  f16x8 v;
  #pragma unroll
  for (int j = 0; j < 8; ++j) {
    int i = hi * 8 + j;
    float x = (i < 16) ? m1w[p * 1024 + i * 64 + col]
            : (i == 16) ? m1b[p * 64 + col] : 0.0f;
    v[j] = (_Float16)x;
  }
  *(f16x8*)(out + (size_t)p * 2048 + t * 8) = v;
}

// head weights -> 8 f16 fragment slices
__global__ __launch_bounds__(256) void prep_headB(
    const float* __restrict__ w0, const float* __restrict__ b0,
    const float* __restrict__ w1, const float* __restrict__ b1,
    _Float16* __restrict__ out)
{
  int s = blockIdx.x;
  int t = threadIdx.x;
  int hi = t >> 6, col = t & 63;
  f16x8 v;
  #pragma unroll
  for (int j = 0; j < 8; ++j) {
    int k = hi * 8 + j;
    float x = 0.0f;
    if (s < 5) {
      int kr = s * 32 + k;
      x = (kr < 144) ? w0[kr * 64 + col] : (kr == 144 ? b0[col] : 0.0f);
    } else {
      int kr = (s - 5) * 32 + k;
      x = (kr < 64) ? w1[kr * 64 + col] : (kr == 64 ? b1[col] : 0.0f);
    }
    v[j] = (_Float16)x;
  }
  *(f16x8*)(out + (size_t)s * 2048 + t * 8) = v;
}

// ---------------- CSR build (edge lists are fixed inputs) ----------------
__global__ __launch_bounds__(256) void count_edges(
    const int* __restrict__ dT, const int* __restrict__ dC,
    int* __restrict__ cT, int* __restrict__ cC)
{
  int i = blockIdx.x * 256 + threadIdx.x;
  if (i < NEDGE) atomicAdd(&cT[dT[i]], 1);
  else { int j = i - NEDGE; if (j < NEDGE) atomicAdd(&cC[dC[j]], 1); }
}

struct ScanArgs { const int* c0; int* o0; int n0; const int* c1; int* o1; int n1; };

// one block per array: exclusive scan of counts -> offsets (off[n] = total)
__global__ __launch_bounds__(1024) void scan2(ScanArgs a) {
  const int* c = blockIdx.x ? a.c1 : a.c0;
  int*       o = blockIdx.x ? a.o1 : a.o0;
  int        n = blockIdx.x ? a.n1 : a.n0;
  __shared__ int lds[1024];
  int t = threadIdx.x;
  int CH = (n + 1023) / 1024;
  int base = t * CH;
  int s = 0;
  for (int i = 0; i < CH; ++i) { int idx = base + i; if (idx < n) s += c[idx]; }
  lds[t] = s;
  __syncthreads();
  #pragma unroll
  for (int d = 1; d < 1024; d <<= 1) {
    int v = (t >= d) ? lds[t - d] : 0;
    __syncthreads();
    lds[t] += v;
    __syncthreads();
  }
  int run = lds[t] - s;   // exclusive prefix
  for (int i = 0; i < CH; ++i) {
    int idx = base + i;
    if (idx < n) { o[idx] = run; run += c[idx]; }
  }
  if (t == 1023) o[n] = lds[1023];
}

__global__ __launch_bounds__(256) void scatter_edges(
    const int* __restrict__ dT, const int* __restrict__ dC,
    const int* __restrict__ oT, const int* __restrict__ oC,
    int* __restrict__ curT, int* __restrict__ curC,
    int* __restrict__ permT, int* __restrict__ permC)
{
  int i = blockIdx.x * 256 + threadIdx.x;
  if (i < NEDGE) {
    int d = dT[i];
    int p = atomicAdd(&curT[d], 1);
    permT[oT[d] + p] = i;
  } else {
    int j = i - NEDGE;
    if (j < NEDGE) {
      int d = dC[j];
      int p = atomicAdd(&curC[d], 1);
      permC[oC[d] + p] = j;
    }
  }
}

// ---- merged node transform: dir0 = customer (blk0 blocks), dir1 = target ----
struct NtArgs {
  const float* emb0; const int* idx0; const float* w0; const float* b0; float* out0; int n0; int blk0;
  const float* emb1; const int* idx1; const float* w1; const float* b1; float* out1; int n1;
};

__global__ __launch_bounds__(256) void node_transform2(NtArgs a) {
  int bid = blockIdx.x;
  int dir = (bid >= a.blk0) ? 1 : 0;
  int lb  = bid - (dir ? a.blk0 : 0);
  const float* emb = dir ? a.emb1 : a.emb0;
  const int*   idx = dir ? a.idx1 : a.idx0;
  const float* w   = dir ? a.w1   : a.w0;
  const float* b   = dir ? a.b1   : a.b0;
  float*       out = dir ? a.out1 : a.out0;
  int          n   = dir ? a.n1   : a.n0;

  __shared__ float s_w[64 * 64];
  __shared__ float s_b[64];
  int tid = threadIdx.x;
  for (int i = tid; i < 4096; i += 256) s_w[i] = w[i];
  if (tid < 64) s_b[tid] = b[tid];
  __syncthreads();
  int wave = tid >> 6, lane = tid & 63;
  int node = lb * 4 + wave;
  if (node >= n) return;
  float v = emb[idx[node] * 64 + lane];
  float acc = s_b[lane];
  #pragma unroll 8
  for (int i = 0; i < 64; ++i)
    acc = fmaf(__shfl(v, i, 64), s_w[i * 64 + lane], acc);
  out[node * 64 + lane] = acc;
}

// ---- merged MFMA NNConv (both directions, grid = 2*EBLK), CSR-ordered ----
// Writes per-slot f32 msg rows (contiguous per dst); NO global atomics.
struct ConvArgs {
  const float* h_src0; const int* esrc0; const float* ea0;
  const int* perm0; const _Float16* B0; const _Float16* m10; float* msg0;
  const float* h_src1; const int* esrc1; const float* ea1;
  const int* perm1; const _Float16* B1; const _Float16* m11; float* msg1;
};

__global__ __launch_bounds__(256) void conv_msg_mfma2(ConvArgs a) {
  __shared__ __align__(16) _Float16 s_B[2][4][2048];   // 32 KB, dbuf x 4 slices
  __shared__ __align__(16) _Float16 s_m1f[2048];
  __shared__ __align__(16) _Float16 s_hidT[64 * HSTRIDE];
  __shared__ int s_srcn[256];
  __shared__ int s_eidx[256];

  const int bid = blockIdx.x;
  const int dir = (bid >= EBLK) ? 1 : 0;
  const int eb  = bid - (dir ? EBLK : 0);

  const float*    h_src  = dir ? a.h_src1 : a.h_src0;
  const int*      esrc   = dir ? a.esrc1  : a.esrc0;
  const float*    eattr  = dir ? a.ea1    : a.ea0;
  const int*      eperm  = dir ? a.perm1  : a.perm0;
  const _Float16* Bready = dir ? a.B1     : a.B0;
  const _Float16* m1rdy  = dir ? a.m11    : a.m10;
  float*          msg    = dir ? a.msg1   : a.msg0;

  const int tid  = threadIdx.x;
  const int e0   = eb * 256;
  const int w    = tid >> 6;
  const int lane = tid & 63;
  const int l15  = lane & 15;
  const int hi   = lane >> 4;
  const int w64  = w * 64;

  // prologue stages: m1 block + K-slices 0..3
  stage16(m1rdy + tid * 8, &s_m1f[tid * 8]);
  #pragma unroll
  for (int q = 0; q < 4; ++q)
    stage16(Bready + (size_t)q * 2048 + tid * 8, &s_B[0][q][tid * 8]);

  {
    int e = eperm[e0 + tid];     // pad slots hold 0 (valid edge; output unread)
    s_eidx[tid] = e;
    s_srcn[tid] = esrc[e];
  }
  __syncthreads();   // full drain: stages + idx visible

  // ---- gather hv into registers (per M-tile, per i-set) ----
  f16x8 hv0[4], hv1[4];
  #pragma unroll
  for (int m = 0; m < 4; ++m) {
    int el = w64 + m * 16 + l15;
    const float* src = h_src + (size_t)s_srcn[el] * 64;
    float4 a0 = *(const float4*)(src + hi * 8);
    float4 a1 = *(const float4*)(src + hi * 8 + 4);
    float4 b0 = *(const float4*)(src + 32 + hi * 8);
    float4 b1 = *(const float4*)(src + 32 + hi * 8 + 4);
    hv0[m] = (f16x8){(_Float16)a0.x,(_Float16)a0.y,(_Float16)a0.z,(_Float16)a0.w,
                     (_Float16)a1.x,(_Float16)a1.y,(_Float16)a1.z,(_Float16)a1.w};
    hv1[m] = (f16x8){(_Float16)b0.x,(_Float16)b0.y,(_Float16)b0.z,(_Float16)b0.w,
                     (_Float16)b1.x,(_Float16)b1.y,(_Float16)b1.z,(_Float16)b1.w};
  }

  // ---- hidden = relu(eattr @ m1w + m1b) via one MFMA K-step ----
  {
    f16x8 ea[4];
    #pragma unroll
    for (int m = 0; m < 4; ++m) {
      int li = w64 + m * 16 + l15;
      int e  = s_eidx[li];
      f16x8 v = {};
      if (hi < 2) {
        float4 f0 = *(const float4*)(eattr + (size_t)e * 16 + hi * 8);
        float4 f1 = *(const float4*)(eattr + (size_t)e * 16 + hi * 8 + 4);
        v = (f16x8){(_Float16)f0.x,(_Float16)f0.y,(_Float16)f0.z,(_Float16)f0.w,
                    (_Float16)f1.x,(_Float16)f1.y,(_Float16)f1.z,(_Float16)f1.w};
      } else if (hi == 2) {
        v[0] = (_Float16)1.0f;    // i==16 -> bias row
      }
      ea[m] = v;
    }
    f32x4 hacc[4][4] = {};
    #pragma unroll
    for (int n = 0; n < 4; ++n) {
      f16x8 bm = *(const f16x8*)&s_m1f[(hi * 64 + n * 16 + l15) * 8];
      #pragma unroll
      for (int m = 0; m < 4; ++m)
        hacc[m][n] = __builtin_amdgcn_mfma_f32_16x16x32_f16(ea[m], bm, hacc[m][n], 0, 0, 0);
    }
    // hidT columns are wave-private
    #pragma unroll
    for (int m = 0; m < 4; ++m) {
      #pragma unroll
      for (int n = 0; n < 4; ++n) {
        int h  = n * 16 + l15;
        int e4 = w64 + m * 16 + hi * 4;
        f16x4 hval;
        #pragma unroll
        for (int r = 0; r < 4; ++r) hval[r] = (_Float16)fmaxf(hacc[m][n][r], 0.0f);
        *(f16x4*)&s_hidT[h * HSTRIDE + e4] = hval;
      }
    }
  }

  f32x4 acc[4][4] = {};

#define MFMA_SLICE(P_, SS, HV, HH)                                            \
  {                                                                           \
    f16x8 b0 = *(const f16x8*)&s_B[P_][SS][(hi * 64 +  0 + l15) * 8];         \
    f16x8 b1 = *(const f16x8*)&s_B[P_][SS][(hi * 64 + 16 + l15) * 8];         \
    f16x8 b2 = *(const f16x8*)&s_B[P_][SS][(hi * 64 + 32 + l15) * 8];         \
    f16x8 b3 = *(const f16x8*)&s_B[P_][SS][(hi * 64 + 48 + l15) * 8];         \
    _Pragma("unroll")                                                         \
    for (int m = 0; m < 4; ++m) {                                             \
      f16x8 av = (f16x8)(HV[m] * HH[m]);                                      \
      acc[m][0] = __builtin_amdgcn_mfma_f32_16x16x32_f16(av, b0, acc[m][0], 0, 0, 0); \
      acc[m][1] = __builtin_amdgcn_mfma_f32_16x16x32_f16(av, b1, acc[m][1], 0, 0, 0); \
      acc[m][2] = __builtin_amdgcn_mfma_f32_16x16x32_f16(av, b2, acc[m][2], 0, 0, 0); \
      acc[m][3] = __builtin_amdgcn_mfma_f32_16x16x32_f16(av, b3, acc[m][3], 0, 0, 0); \
    }                                                                         \
  }

#define BIAS_SLICE(P_, SS, HV)                                                \
  {                                                                           \
    f16x8 b0 = *(const f16x8*)&s_B[P_][SS][(hi * 64 +  0 + l15) * 8];         \
    f16x8 b1 = *(const f16x8*)&s_B[P_][SS][(hi * 64 + 16 + l15) * 8];         \
    f16x8 b2 = *(const f16x8*)&s_B[P_][SS][(hi * 64 + 32 + l15) * 8];         \
    f16x8 b3 = *(const f16x8*)&s_B[P_][SS][(hi * 64 + 48 + l15) * 8];         \
    _Pragma("unroll")                                                         \
    for (int m = 0; m < 4; ++m) {                                             \
      f16x8 av = HV[m];                                                       \
      acc[m][0] = __builtin_amdgcn_mfma_f32_16x16x32_f16(av, b0, acc[m][0], 0, 0, 0); \
      acc[m][1] = __builtin_amdgcn_mfma_f32_16x16x32_f16(av, b1, acc[m][1], 0, 0, 0); \
      acc[m][2] = __builtin_amdgcn_mfma_f32_16x16x32_f16(av, b2, acc[m][2], 0, 0, 0); \
      acc[m][3] = __builtin_amdgcn_mfma_f32_16x16x32_f16(av, b3, acc[m][3], 0, 0, 0); \
    }                                                                         \
  }

  // ---- phase loop: p=0..31 full (4 slices), p=32 bias (2 slices) ----
  for (int p = 0; p < 33; ++p) {
    const int P = p & 1;
    if (p < 31) {
      #pragma unroll
      for (int q = 0; q < 4; ++q)
        stage16(Bready + (size_t)(4 * p + 4 + q) * 2048 + tid * 8,
                &s_B[P ^ 1][q][tid * 8]);
    } else if (p == 31) {
      stage16(Bready + (size_t)128 * 2048 + tid * 8, &s_B[P ^ 1][0][tid * 8]);
      stage16(Bready + (size_t)129 * 2048 + tid * 8, &s_B[P ^ 1][1][tid * 8]);
    }
    if (p < 32) {
      _Float16 hA[4], hB[4];
      #pragma unroll
      for (int m = 0; m < 4; ++m)
        hA[m] = s_hidT[(2 * p) * HSTRIDE + w64 + m * 16 + l15];
      #pragma unroll
      for (int m = 0; m < 4; ++m)
        hB[m] = s_hidT[(2 * p + 1) * HSTRIDE + w64 + m * 16 + l15];
      MFMA_SLICE(P, 0, hv0, hA);
      MFMA_SLICE(P, 1, hv1, hA);
      MFMA_SLICE(P, 2, hv0, hB);
      MFMA_SLICE(P, 3, hv1, hB);
    } else {
      BIAS_SLICE(P, 0, hv0);
      BIAS_SLICE(P, 1, hv1);
    }
    asm volatile("s_waitcnt vmcnt(0)" ::: "memory");
    __builtin_amdgcn_s_barrier();
  }
#undef MFMA_SLICE
#undef BIAS_SLICE

  // ---- epilogue: plain coalesced f32 msg stores (slot-ordered) ----
  #pragma unroll
  for (int m = 0; m < 4; ++m) {
    #pragma unroll
    for (int r = 0; r < 4; ++r) {
      int sl = e0 + w64 + m * 16 + hi * 4 + r;
      float* row = msg + (size_t)sl * 64;
      #pragma unroll
      for (int n = 0; n < 4; ++n)
        row[n * 16 + l15] = acc[m][n][r];
    }
  }
}

// ---- fused segment-max + root transform + relu (both directions) ----
struct SegArgs {
  const float* msg0; const int* off0; const float* hold0; const float* rw0; const float* rb0;
  float* hnew0; int n0; int blk0;
  const float* msg1; const int* off1; const float* hold1; const float* rw1; const float* rb1;
  float* hnew1; int n1;
};

__global__ __launch_bounds__(256) void segfin2(SegArgs a) {
  int bid = blockIdx.x;
  int dir = (bid >= a.blk0) ? 1 : 0;
  int lb  = bid - (dir ? a.blk0 : 0);
  const float* msg  = dir ? a.msg1  : a.msg0;
  const int*   off  = dir ? a.off1  : a.off0;
  const float* hold = dir ? a.hold1 : a.hold0;
  const float* rw   = dir ? a.rw1   : a.rw0;
  const float* rb   = dir ? a.rb1   : a.rb0;
  float*       hnew = dir ? a.hnew1 : a.hnew0;
  int          n    = dir ? a.n1    : a.n0;

  __shared__ float s_w[64 * 64];
  __shared__ float s_b[64];
  int tid = threadIdx.x;
  for (int i = tid; i < 4096; i += 256) s_w[i] = rw[i];
  if (tid < 64) s_b[tid] = rb[tid];
  __syncthreads();
  int wave = tid >> 6, lane = tid & 63;
  int node = lb * 4 + wave;
  if (node >= n) return;

  int k0 = off[node], k1 = off[node + 1];
  float mx = -INFINITY;
  for (int k = k0; k < k1; ++k)
    mx = fmaxf(mx, msg[(size_t)k * 64 + lane]);
  if (k0 == k1) mx = 0.0f;          // isolated node -> 0 (PyG semantics)

  float v = hold[node * 64 + lane];
  float acc = s_b[lane];
  #pragma unroll 8
  for (int i = 0; i < 64; ++i)
    acc = fmaf(__shfl(v, i, 64), s_w[i * 64 + lane], acc);
  hnew[node * 64 + lane] = fmaxf(mx + acc, 0.0f);
}

// ---- MFMA predictor head: 128 edges/block (4 waves x 32 edges) ----
__global__ __launch_bounds__(256) void head_mfma(
    const float* __restrict__ h_c, const float* __restrict__ h_t,
    const int* __restrict__ lsrc, const int* __restrict__ ldst,
    const float* __restrict__ lattr,
    const _Float16* __restrict__ headB,   // 8*2048 halves
    const float* __restrict__ w2, const float* __restrict__ b2,
    float* __restrict__ preds, float* __restrict__ logits, int nL)
{
  __shared__ __align__(16) _Float16 s_W[8][2048];     // 32KB
  __shared__ __align__(16) _Float16 s_z[4][32][ZSTR]; // wave-private rows
  __shared__ float s_w2[64];

  const int tid = threadIdx.x;
  const int wv = tid >> 6, lane = tid & 63;
  const int l15 = lane & 15, hi = lane >> 4;

  #pragma unroll
  for (int s = 0; s < 8; ++s)
    stage16(headB + s * 2048 + tid * 8, &s_W[s][tid * 8]);
  if (tid < 64) s_w2[tid] = w2[tid];
  const float b2v = b2[0];

  const int e0 = blockIdx.x * 128 + wv * 32;

  f16x8 ac[2][2], at[2][2], aa[2];
  #pragma unroll
  for (int m = 0; m < 2; ++m) {
    int e = e0 + m * 16 + l15;
    int ee = (e < nL) ? e : 0;
    const float* pc = h_c + (size_t)lsrc[ee] * 64;
    const float* pt = h_t + (size_t)ldst[ee] * 64;
    #pragma unroll
    for (int half = 0; half < 2; ++half) {
      float4 c0 = *(const float4*)(pc + half * 32 + hi * 8);
      float4 c1 = *(const float4*)(pc + half * 32 + hi * 8 + 4);
      float4 t0 = *(const float4*)(pt + half * 32 + hi * 8);
      float4 t1 = *(const float4*)(pt + half * 32 + hi * 8 + 4);
      ac[m][half] = (f16x8){(_Float16)c0.x,(_Float16)c0.y,(_Float16)c0.z,(_Float16)c0.w,
                            (_Float16)c1.x,(_Float16)c1.y,(_Float16)c1.z,(_Float16)c1.w};
      at[m][half] = (f16x8){(_Float16)t0.x,(_Float16)t0.y,(_Float16)t0.z,(_Float16)t0.w,
                            (_Float16)t1.x,(_Float16)t1.y,(_Float16)t1.z,(_Float16)t1.w};
    }
    f16x8 v = {};
    if (hi < 2) {
      float4 f0 = *(const float4*)(lattr + (size_t)ee * 16 + hi * 8);
      float4 f1 = *(const float4*)(lattr + (size_t)ee * 16 + hi * 8 + 4);
      v = (f16x8){(_Float16)f0.x,(_Float16)f0.y,(_Float16)f0.z,(_Float16)f0.w,
                  (_Float16)f1.x,(_Float16)f1.y,(_Float16)f1.z,(_Float16)f1.w};
    } else if (hi == 2) {
      v[0] = (_Float16)1.0f;   // krow 144 = bias
    }
    aa[m] = v;
  }

  __syncthreads();   // weights staged

  f32x4 acc1[2][4] = {};
  #pragma unroll
  for (int s = 0; s < 5; ++s) {
    f16x8 bfr[4];
    #pragma unroll
    for (int nn = 0; nn < 4; ++nn)
      bfr[nn] = *(const f16x8*)&s_W[s][(hi * 64 + nn * 16 + l15) * 8];
    #pragma unroll
    for (int m = 0; m < 2; ++m) {
      f16x8 a = (s == 0) ? ac[m][0] : (s == 1) ? ac[m][1]
              : (s == 2) ? at[m][0] : (s == 3) ? at[m][1] : aa[m];
      #pragma unroll
      for (int nn = 0; nn < 4; ++nn)
        acc1[m][nn] = __builtin_amdgcn_mfma_f32_16x16x32_f16(a, bfr[nn], acc1[m][nn], 0, 0, 0);
    }
  }

  #pragma unroll
  for (int m = 0; m < 2; ++m)
    #pragma unroll
    for (int nn = 0; nn < 4; ++nn)
      #pragma unroll
      for (int r = 0; r < 4; ++r)
        s_z[wv][m * 16 + hi * 4 + r][nn * 16 + l15] =
            (_Float16)fmaxf(acc1[m][nn][r], 0.0f);

  f16x8 abias = {};
  if (hi == 0) abias[0] = (_Float16)1.0f;   // krow2 64 = bias
  f32x4 acc2[2][4] = {};
  #pragma unroll
  for (int s = 0; s < 3; ++s) {
    f16x8 bfr[4];
    #pragma unroll
    for (int nn = 0; nn < 4; ++nn)
      bfr[nn] = *(const f16x8*)&s_W[5 + s][(hi * 64 + nn * 16 + l15) * 8];
    #pragma unroll
    for (int m = 0; m < 2; ++m) {
      f16x8 a = (s < 2) ? *(const f16x8*)&s_z[wv][m * 16 + l15][s * 32 + hi * 8] : abias;
      #pragma unroll
      for (int nn = 0; nn < 4; ++nn)
        acc2[m][nn] = __builtin_amdgcn_mfma_f32_16x16x32_f16(a, bfr[nn], acc2[m][nn], 0, 0, 0);
    }
  }

  #pragma unroll
  for (int m = 0; m < 2; ++m) {
    float part[4];
    #pragma unroll
    for (int r = 0; r < 4; ++r) {
      float p = 0.0f;
      #pragma unroll
      for (int nn = 0; nn < 4; ++nn)
        p = fmaf(fmaxf(acc2[m][nn][r], 0.0f), s_w2[nn * 16 + l15], p);
      part[r] = p;
    }
    #pragma unroll
    for (int off = 1; off < 16; off <<= 1) {
      #pragma unroll
      for (int r = 0; r < 4; ++r)
        part[r] += __shfl_xor(part[r], off, 64);
    }
    if (l15 == 0) {
      #pragma unroll
      for (int r = 0; r < 4; ++r) {
        int e = e0 + m * 16 + hi * 4 + r;
        if (e < nL) {
          float lg = part[r] + b2v;
          logits[e] = lg;
          preds[e]  = 1.0f / (1.0f + expf(-lg));
        }
      }
    }
  }
}

extern "C" void kernel_launch(void* const* d_in, const int* in_sizes, int n_in,
                              void* d_out, int out_size, void* d_ws, size_t ws_size,
                              hipStream_t stream) {
  const int*   x_c      = (const int*)  d_in[0];
  const int*   x_t      = (const int*)  d_in[1];
  const int*   esrc_ct  = (const int*)  d_in[2];
  const int*   edst_ct  = (const int*)  d_in[3];
  const int*   esrc_tc  = (const int*)  d_in[4];
  const int*   edst_tc  = (const int*)  d_in[5];
  const int*   lbl_src  = (const int*)  d_in[6];
  const int*   lbl_dst  = (const int*)  d_in[7];
  const float* eattr_ct = (const float*)d_in[8];
  const float* eattr_tc = (const float*)d_in[9];
  const float* lbl_attr = (const float*)d_in[10];
  const float* emb_c    = (const float*)d_in[11];
  const float* emb_t    = (const float*)d_in[12];
  const float* ntl_c_w  = (const float*)d_in[13];
  const float* ntl_c_b  = (const float*)d_in[14];
  const float* ntl_t_w  = (const float*)d_in[15];
  const float* ntl_t_b  = (const float*)d_in[16];
  const float* m1w      = (const float*)d_in[17];  // (2,2,16,64)
  const float* m1b      = (const float*)d_in[18];  // (2,2,64)
  const float* m2w      = (const float*)d_in[19];  // (2,2,64,4096)
  const float* m2b      = (const float*)d_in[20];  // (2,2,4096)
  const float* rw       = (const float*)d_in[21];  // (2,2,64,64)
  const float* rb       = (const float*)d_in[22];  // (2,2,64)
  const float* ph_w0    = (const float*)d_in[23];
  const float* ph_b0    = (const float*)d_in[24];
  const float* ph_w1    = (const float*)d_in[25];
  const float* ph_b1    = (const float*)d_in[26];
  const float* ph_w2    = (const float*)d_in[27];
  const float* ph_b2    = (const float*)d_in[28];

  float* out = (float*)d_out;

  // ---------------- workspace layout ----------------
  float* ws = (float*)d_ws;
  float* h_c0 = ws;                          // 320000
  float* h_c1 = h_c0 + NCN * 64;
  float* h_t0 = h_c1 + NCN * 64;             // 640000
  float* h_t1 = h_t0 + NTN * 64;
  float* msgT = h_t1 + NTN * 64;             // ESLOT*64 (ct -> target dst)
  float* msgC = msgT + (size_t)ESLOT * 64;   // ESLOT*64 (tc -> customer dst)
  _Float16* Bready  = (_Float16*)(msgC + (size_t)ESLOT * 64);  // 4*130*2048 h
  _Float16* m1ready = Bready + 4 * NSLICE * 2048;              // 4*2048 h
  _Float16* headBr  = m1ready + 4 * 2048;                      // 8*2048 h
  int* ip     = (int*)(headBr + 8 * 2048);
  int* offT   = ip;               ip += NTN + 1;
  int* offC   = ip;               ip += NCN + 1;
  // zeroed region start:
  int* cntT   = ip;               ip += NTN;
  int* cntC   = ip;               ip += NCN;
  int* curT   = ip;               ip += NTN;
  int* curC   = ip;               ip += NCN;
  int* permT  = ip;               ip += ESLOT;
  int* permC  = ip;               ip += ESLOT;
  size_t zero_bytes = (size_t)(2 * (NTN + NCN) + 2 * ESLOT) * sizeof(int);

  // ---------------- CSR build (same for both layers) ----------------
  hipMemsetAsync(cntT, 0, zero_bytes, stream);
  count_edges<<<(2 * NEDGE + 255) / 256, 256, 0, stream>>>(edst_ct, edst_tc, cntT, cntC);
  {
    ScanArgs sa; sa.c0 = cntT; sa.o0 = offT; sa.n0 = NTN;
    sa.c1 = cntC; sa.o1 = offC; sa.n1 = NCN;
    scan2<<<2, 1024, 0, stream>>>(sa);
  }
  scatter_edges<<<(2 * NEDGE + 255) / 256, 256, 0, stream>>>(
      edst_ct, edst_tc, offT, offC, curT, curC, permT, permC);

  // ---------------- weight prep ----------------
  prep_B    <<<4 * NSLICE, 256, 0, stream>>>(m2w, m2b, Bready);
  prep_m1   <<<4, 256, 0, stream>>>(m1w, m1b, m1ready);
  prep_headB<<<8, 256, 0, stream>>>(ph_w0, ph_b0, ph_w1, ph_b1, headBr);

  // ---------------- node transforms ----------------
  {
    NtArgs na;
    na.emb0 = emb_c; na.idx0 = x_c; na.w0 = ntl_c_w; na.b0 = ntl_c_b; na.out0 = h_c0; na.n0 = NCN;
    na.blk0 = (NCN + 3) / 4;
    na.emb1 = emb_t; na.idx1 = x_t; na.w1 = ntl_t_w; na.b1 = ntl_t_b; na.out1 = h_t0; na.n1 = NTN;
    node_transform2<<<(NCN + 3) / 4 + (NTN + 3) / 4, 256, 0, stream>>>(na);
  }

  float* hc_cur = h_c0; float* hc_nxt = h_c1;
  float* ht_cur = h_t0; float* ht_nxt = h_t1;

  for (int l = 0; l < 2; ++l) {
    int p0 = l * 2 + 0;   // ct direction (writes to t)
    int p1 = l * 2 + 1;   // tc direction (writes to c)
    {
      ConvArgs ca;
      ca.h_src0 = hc_cur; ca.esrc0 = esrc_ct; ca.ea0 = eattr_ct; ca.perm0 = permT;
      ca.B0 = Bready + (size_t)p0 * NSLICE * 2048; ca.m10 = m1ready + (size_t)p0 * 2048;
      ca.msg0 = msgT;
      ca.h_src1 = ht_cur; ca.esrc1 = esrc_tc; ca.ea1 = eattr_tc; ca.perm1 = permC;
      ca.B1 = Bready + (size_t)p1 * NSLICE * 2048; ca.m11 = m1ready + (size_t)p1 * 2048;
      ca.msg1 = msgC;
      conv_msg_mfma2<<<2 * EBLK, 256, 0, stream>>>(ca);
    }
    {
      SegArgs sg;
      sg.msg0 = msgT; sg.off0 = offT; sg.hold0 = ht_cur;
      sg.rw0 = rw + p0 * 4096; sg.rb0 = rb + p0 * 64; sg.hnew0 = ht_nxt;
      sg.n0 = NTN; sg.blk0 = (NTN + 3) / 4;
      sg.msg1 = msgC; sg.off1 = offC; sg.hold1 = hc_cur;
      sg.rw1 = rw + p1 * 4096; sg.rb1 = rb + p1 * 64; sg.hnew1 = hc_nxt;
      sg.n1 = NCN;
      segfin2<<<(NTN + 3) / 4 + (NCN + 3) / 4, 256, 0, stream>>>(sg);
    }
    float* t;
    t = hc_cur; hc_cur = hc_nxt; hc_nxt = t;
    t = ht_cur; ht_cur = ht_nxt; ht_nxt = t;
  }

  head_mfma<<<(NLBL + 127) / 128, 256, 0, stream>>>(
      hc_cur, ht_cur, lbl_src, lbl_dst, lbl_attr,
      headBr, ph_w2, ph_b2,
      out, out + NLBL, NLBL);
}